// Round 12
// baseline (423.930 us; speedup 1.0000x reference)
//
#include <hip/hip_runtime.h>
#include <hip/hip_bf16.h>
#include <cstdint>

#define NLOC 128        // nodes per graph
#define NGRAPH 128      // bs*T
#define NNODE 16384     // total nodes
#define EBASE 2048      // base edges per graph
#define CSTRIDE 256     // csr col stride per local node

typedef _Float16 half2v __attribute__((ext_vector_type(2)));

__device__ __forceinline__ float sigf(float x) { return 1.f / (1.f + __expf(-x)); }
__device__ __forceinline__ float tanhfast(float x) {
    float e = __expf(2.f * x);
    return 1.f - 2.f / (e + 1.f);
}
__device__ __forceinline__ uint32_t packh2(float a, float b) {
    half2v v;
    v.x = (_Float16)a; v.y = (_Float16)b;
    return __builtin_bit_cast(uint32_t, v);
}
__device__ __forceinline__ float dot2(uint32_t w, uint32_t h, float acc) {
#if __has_builtin(__builtin_amdgcn_fdot2)
    return __builtin_amdgcn_fdot2(__builtin_bit_cast(half2v, w),
                                  __builtin_bit_cast(half2v, h), acc, false);
#else
    half2v wv = __builtin_bit_cast(half2v, w);
    half2v hv = __builtin_bit_cast(half2v, h);
    return acc + (float)wv.x * (float)hv.x + (float)wv.y * (float)hv.y;
#endif
}

// ---------------- CSR of the shared per-graph edge list (dst -> list of src) --------------
__global__ __launch_bounds__(256) void build_csr_kernel(const int* __restrict__ ei,
                                                        int* __restrict__ cnt,
                                                        int* __restrict__ col) {
    __shared__ int m_l[256];
    int v = blockIdx.x, j = threadIdx.x;
    const int* srcs = ei;
    const int* dsts = ei + EBASE;
    int e0 = j * 8;
    int d[8];
#pragma unroll
    for (int k = 0; k < 8; ++k) d[k] = dsts[e0 + k];
    int mycnt = 0;
#pragma unroll
    for (int k = 0; k < 8; ++k) mycnt += (d[k] == v);
    m_l[j] = mycnt;
    __syncthreads();
    int start = 0;
    for (int q = 0; q < 256; ++q) {
        int mv = m_l[q];
        if (q < j) start += mv;
    }
    if (j == 255) cnt[v] = start + mycnt;
    int w = v * CSTRIDE + start;
#pragma unroll
    for (int k = 0; k < 8; ++k) {
        if (d[k] == v) col[w++] = srcs[e0 + k];
    }
}

// ---------------- fp32 GEMM 128x128 tile, 8x8 micro-tile ----------------
__global__ __launch_bounds__(256) void gemm128_kernel(const float* __restrict__ A,
                                                      const float* __restrict__ B,
                                                      float* __restrict__ C,
                                                      int M, int N, int K) {
    __shared__ __align__(16) float As[16][128];   // [k][m]
    __shared__ __align__(16) float Bs[16][128];   // [k][n]
    int tid = threadIdx.x;
    int bm = blockIdx.y, bn = blockIdx.x;
    int ar = tid >> 1, ak = (tid & 1) * 8;
    int bk = tid >> 4, bc = (tid & 15) * 8;
    int ty = tid >> 4, tx = tid & 15;
    const float* Ab = A + (size_t)(bm * 128 + ar) * K;
    const float* Bb = B + (size_t)bn * 128 + bc;
    float acc[8][8] = {};
    for (int k0 = 0; k0 < K; k0 += 16) {
        float4 a0 = *(const float4*)(Ab + k0 + ak);
        float4 a1 = *(const float4*)(Ab + k0 + ak + 4);
        float4 b0 = *(const float4*)(Bb + (size_t)(k0 + bk) * N);
        float4 b1 = *(const float4*)(Bb + (size_t)(k0 + bk) * N + 4);
        As[ak + 0][ar] = a0.x; As[ak + 1][ar] = a0.y; As[ak + 2][ar] = a0.z; As[ak + 3][ar] = a0.w;
        As[ak + 4][ar] = a1.x; As[ak + 5][ar] = a1.y; As[ak + 6][ar] = a1.z; As[ak + 7][ar] = a1.w;
        *(float4*)&Bs[bk][bc] = b0;
        *(float4*)&Bs[bk][bc + 4] = b1;
        __syncthreads();
#pragma unroll
        for (int kk = 0; kk < 16; ++kk) {
            float4 x0 = *(const float4*)&As[kk][ty * 8];
            float4 x1 = *(const float4*)&As[kk][ty * 8 + 4];
            float4 y0 = *(const float4*)&Bs[kk][tx * 8];
            float4 y1 = *(const float4*)&Bs[kk][tx * 8 + 4];
            float xa[8] = {x0.x, x0.y, x0.z, x0.w, x1.x, x1.y, x1.z, x1.w};
            float yb[8] = {y0.x, y0.y, y0.z, y0.w, y1.x, y1.y, y1.z, y1.w};
#pragma unroll
            for (int i = 0; i < 8; ++i)
#pragma unroll
                for (int j = 0; j < 8; ++j) acc[i][j] += xa[i] * yb[j];
        }
        __syncthreads();
    }
    float* Cb = C + (size_t)(bm * 128 + ty * 8) * N + (size_t)bn * 128 + tx * 8;
#pragma unroll
    for (int i = 0; i < 8; ++i) {
        *(float4*)(Cb + (size_t)i * N) = make_float4(acc[i][0], acc[i][1], acc[i][2], acc[i][3]);
        *(float4*)(Cb + (size_t)i * N + 4) = make_float4(acc[i][4], acc[i][5], acc[i][6], acc[i][7]);
    }
}

// ---------------- fp32 tiled GEMM 64x64 (N=64 layer-3) ----------------
__global__ __launch_bounds__(256) void gemm_kernel(const float* __restrict__ A,
                                                   const float* __restrict__ B,
                                                   float* __restrict__ C,
                                                   int M, int N, int K) {
    __shared__ __align__(16) float As[16][64];
    __shared__ __align__(16) float Bs[16][64];
    int tid = threadIdx.x;
    int bm = blockIdx.y, bn = blockIdx.x;
    int am = tid >> 2, ak = (tid & 3) << 2;
    int bk = tid >> 4, bn4 = (tid & 15) << 2;
    int ty = tid >> 4, tx = tid & 15;
    const float* Ab = A + (size_t)bm * 64 * K;
    const float* Bb = B + bn * 64;
    float acc[4][4] = {};
    for (int k0 = 0; k0 < K; k0 += 16) {
        float4 av = *(const float4*)(Ab + (size_t)am * K + k0 + ak);
        float4 bv = *(const float4*)(Bb + (size_t)(k0 + bk) * N + bn4);
        As[ak + 0][am] = av.x; As[ak + 1][am] = av.y;
        As[ak + 2][am] = av.z; As[ak + 3][am] = av.w;
        *(float4*)&Bs[bk][bn4] = bv;
        __syncthreads();
#pragma unroll
        for (int kk = 0; kk < 16; ++kk) {
            float4 a4 = *(const float4*)&As[kk][ty << 2];
            float4 b4 = *(const float4*)&Bs[kk][tx << 2];
            acc[0][0] += a4.x * b4.x; acc[0][1] += a4.x * b4.y; acc[0][2] += a4.x * b4.z; acc[0][3] += a4.x * b4.w;
            acc[1][0] += a4.y * b4.x; acc[1][1] += a4.y * b4.y; acc[1][2] += a4.y * b4.z; acc[1][3] += a4.y * b4.w;
            acc[2][0] += a4.z * b4.x; acc[2][1] += a4.z * b4.y; acc[2][2] += a4.z * b4.z; acc[2][3] += a4.z * b4.w;
            acc[3][0] += a4.w * b4.x; acc[3][1] += a4.w * b4.y; acc[3][2] += a4.w * b4.z; acc[3][3] += a4.w * b4.w;
        }
        __syncthreads();
    }
    float* Cb = C + (size_t)(bm * 64 + ty * 4) * N + bn * 64 + tx * 4;
#pragma unroll
    for (int i = 0; i < 4; ++i)
        *(float4*)(Cb + (size_t)i * N) = make_float4(acc[i][0], acc[i][1], acc[i][2], acc[i][3]);
}

// ---------------- GAT aggregation v5: 512 thr, 4-way ILP edge loop ------------------------
// R11 analysis: v4's edge loop was a serial chain of DEPENDENT LDS reads (u -> Hs[u],
// ~130cy each, runtime trip count -> no unroll). v5: read u[k0..k0+3] as ONE b128
// broadcast, then 4 INDEPENDENT gather+exp+acc slots (masked tail) -> 4x ILP. 512 thr
// keeps the 128-reg tier (R4) so the unrolled accumulators don't spill; 8 waves/CU.
template <int H>
__global__ __launch_bounds__(512) void agg_kernel(const float* __restrict__ hf,
                                                  const float* __restrict__ a_s,
                                                  const float* __restrict__ a_d,
                                                  const int* __restrict__ cnt,
                                                  const int* __restrict__ col,
                                                  const float* __restrict__ bias,
                                                  float* __restrict__ out) {
    __shared__ float Hs[128][64][H];               // 128 KB (H=4) / 32 KB (H=1)
    __shared__ __align__(16) float as_l[128][H];
    __shared__ __align__(16) float ad_l[128][H];
    __shared__ __align__(16) int u_lds[8][96];
    int g = blockIdx.x, tid = threadIdx.x;
    int lane = tid & 63, w = tid >> 6;             // 8 waves
    int base = g * 128;
    for (int n = w; n < 128; n += 8) {
        const float* row = hf + (size_t)(base + n) * (H * 64);
#pragma unroll
        for (int h = 0; h < H; ++h) {
            float val = row[h * 64 + lane];
            Hs[n][lane][h] = val;
            float ps = val * a_s[h * 64 + lane];
            float pd = val * a_d[h * 64 + lane];
#pragma unroll
            for (int off = 32; off > 0; off >>= 1) {
                ps += __shfl_xor(ps, off, 64);
                pd += __shfl_xor(pd, off, 64);
            }
            if (lane == 0) { as_l[n][h] = ps; ad_l[n][h] = pd; }
        }
    }
    __syncthreads();
    float bset[H];
#pragma unroll
    for (int h = 0; h < H; ++h) bset[h] = bias[h * 64 + lane];
    for (int v = w; v < 128; v += 8) {             // wave-private, no barriers
        int deg = cnt[v];
        int tot = min(deg + 1, 96);
        // fill u_lds fully (pad with self -> safe addresses; padded slots masked below)
        {
            int k0 = lane, k1 = lane + 64;
            u_lds[w][k0] = (k0 < deg) ? col[v * CSTRIDE + k0] : v;
            if (k1 < 96) u_lds[w][k1] = (k1 < deg) ? col[v * CSTRIDE + k1] : v;
        }
        float adv[H], den[H], acc[H];
#pragma unroll
        for (int h = 0; h < H; ++h) { adv[h] = ad_l[v][h]; den[h] = 0.f; acc[h] = 0.f; }
        for (int k0 = 0; k0 < tot; k0 += 4) {
            int4 u4 = *(const int4*)&u_lds[w][k0 & ~3];   // one b128 broadcast per 4 edges
#pragma unroll
            for (int s = 0; s < 4; ++s) {
                int k = k0 + s;
                int u = (s == 0) ? u4.x : (s == 1) ? u4.y : (s == 2) ? u4.z : u4.w;
                float msk = (k < tot) ? 1.f : 0.f;
                float hr[H], asv[H];
                if constexpr (H == 4) {
                    float4 t = *(const float4*)&Hs[u][lane][0];     // independent b128
                    hr[0] = t.x; hr[1] = t.y; hr[2] = t.z; hr[3] = t.w;
                    float4 sv = *(const float4*)&as_l[u][0];
                    asv[0] = sv.x; asv[1] = sv.y; asv[2] = sv.z; asv[3] = sv.w;
                } else {
#pragma unroll
                    for (int h = 0; h < H; ++h) { hr[h] = Hs[u][lane][h]; asv[h] = as_l[u][h]; }
                }
#pragma unroll
                for (int h = 0; h < H; ++h) {
                    float e = asv[h] + adv[h];
                    e = (e > 0.f) ? e : 0.2f * e;
                    float ex = __expf(e) * msk;
                    den[h] += ex;
                    acc[h] += ex * hr[h];
                }
            }
        }
        int n = base + v;
#pragma unroll
        for (int h = 0; h < H; ++h) {
            float o = acc[h] / (den[h] + 1e-16f) + bset[h];
            out[(size_t)n * (H * 64) + h * 64 + lane] = fmaxf(o, 0.f);
        }
    }
}

// ---------------- fused pool + LSTM input part --------------------------------------------
__global__ __launch_bounds__(256) void poolx_kernel(const float* __restrict__ h,
                                                    const float* __restrict__ Wf, const float* __restrict__ bif, const float* __restrict__ bhf,
                                                    const float* __restrict__ Wb, const float* __restrict__ bib, const float* __restrict__ bhb,
                                                    float* __restrict__ xp) {
    __shared__ float part_l[4][64];
    __shared__ float emb[64];
    int g = blockIdx.x, tid = threadIdx.x;
    int c = tid & 63, prt = tid >> 6;
    {
        const float* p = h + (size_t)g * 8192 + prt * 32 * 64 + c;
        float s = 0.f;
#pragma unroll
        for (int vv = 0; vv < 32; ++vv) s += p[vv * 64];
        part_l[prt][c] = s;
    }
    __syncthreads();
    if (tid < 64) emb[tid] = part_l[0][tid] + part_l[1][tid] + part_l[2][tid] + part_l[3][tid];
    __syncthreads();
    int r = (g & 31) * 4 + (g >> 5);
    for (int dir = 0; dir < 2; ++dir) {
        const float* W = dir ? Wb : Wf;
        const float* bi = dir ? bib : bif;
        const float* bh = dir ? bhb : bhf;
        for (int o = tid; o < 1024; o += 256) {
            const float* wr = W + (size_t)o * 64;
            float s = bi[o] + bh[o];
#pragma unroll
            for (int k = 0; k < 64; k += 4) {
                float4 wv = *(const float4*)(wr + k);
                s += emb[k] * wv.x + emb[k + 1] * wv.y + emb[k + 2] * wv.z + emb[k + 3] * wv.w;
            }
            xp[dir * 131072 + r * 1024 + o] = s;
        }
    }
}

// ---------------- pre-pack Whh to f16 pairs (v7 layout) ----------------------------------
__global__ __launch_bounds__(256) void wpack_kernel(const float* __restrict__ Whh_f,
                                                    const float* __restrict__ Whh_b,
                                                    uint32_t* __restrict__ wreg,
                                                    uint32_t* __restrict__ wtail) {
    int gid = blockIdx.x * 256 + threadIdx.x;   // 0..2047
    int dir = gid >> 10, row = gid & 1023;
    const float* src = (dir ? Whh_b : Whh_f) + (size_t)row * 256;
    uint4* wr4 = (uint4*)wreg;
#pragma unroll
    for (int i = 0; i < 24; ++i) {
        uint4 v;
        v.x = packh2(src[i * 8 + 0], src[i * 8 + 1]);
        v.y = packh2(src[i * 8 + 2], src[i * 8 + 3]);
        v.z = packh2(src[i * 8 + 4], src[i * 8 + 5]);
        v.w = packh2(src[i * 8 + 6], src[i * 8 + 7]);
        wr4[(size_t)(dir * 24 + i) * 1024 + row] = v;
    }
    uint4* wt4 = (uint4*)wtail;
#pragma unroll
    for (int ku = 0; ku < 8; ++ku) {
        const float* s8 = src + 192 + ku * 8;
        uint4 v;
        v.x = packh2(s8[0], s8[1]);
        v.y = packh2(s8[2], s8[3]);
        v.z = packh2(s8[4], s8[5]);
        v.w = packh2(s8[6], s8[7]);
        wt4[(size_t)(dir * 8 + ku) * 1024 + row] = v;
    }
}

// ---------------- BiLSTM recurrent v7 (reverted from v8: readlane cost == LDS cost, R11) --
__global__ __launch_bounds__(1024, 1) void lstm_kernel(const float* __restrict__ xp,
                                                       const uint32_t* __restrict__ wreg,
                                                       const uint32_t* __restrict__ wtail,
                                                       float* __restrict__ hT) {
    int blk = blockIdx.x;
    int dir = blk >> 2, batch = blk & 3;
    int t = threadIdx.x;                      // gate row 0..1023
    uint32_t wa[96];
    {
        const uint4* ra = (const uint4*)wreg + (size_t)dir * 24 * 1024;
#pragma unroll
        for (int i = 0; i < 24; ++i) {
            uint4 v = ra[i * 1024 + t];
            wa[i * 4 + 0] = v.x; wa[i * 4 + 1] = v.y; wa[i * 4 + 2] = v.z; wa[i * 4 + 3] = v.w;
        }
    }
    __shared__ __align__(16) uint4 wlds[8 * 1024];   // 128 KB tail, [ku][row]
    __shared__ __align__(16) uint32_t h_pk[128];     // h as 128 half2 pairs
    __shared__ float gv[1024];
    {
        const uint4* tsrc = (const uint4*)wtail + (size_t)dir * 8 * 1024;
        for (int i = t; i < 8 * 1024; i += 1024) wlds[i] = tsrc[i];
    }
    if (t < 128) h_pk[t] = 0;
    __syncthreads();
    float creg = 0.f;
    const float* xpb = xp + dir * 131072 + batch * 1024;
#pragma unroll 1
    for (int step = 0; step < 32; ++step) {
        int teff = dir ? (31 - step) : step;
        float xa = xpb[teff * 4096 + t];
        float acc = 0.f;
#pragma unroll
        for (int q = 0; q < 24; ++q) {
            uint4 hq = *(const uint4*)&h_pk[q * 4];   // same-address broadcast b128
            acc = dot2(wa[q * 4 + 0], hq.x, acc);
            acc = dot2(wa[q * 4 + 1], hq.y, acc);
            acc = dot2(wa[q * 4 + 2], hq.z, acc);
            acc = dot2(wa[q * 4 + 3], hq.w, acc);
        }
#pragma unroll
        for (int ku = 0; ku < 8; ++ku) {
            uint4 hq = *(const uint4*)&h_pk[96 + ku * 4];  // broadcast b128
            uint4 qa = wlds[ku * 1024 + t];                // conflict-free b128
            acc = dot2(qa.x, hq.x, acc); acc = dot2(qa.y, hq.y, acc);
            acc = dot2(qa.z, hq.z, acc); acc = dot2(qa.w, hq.w, acc);
        }
        gv[t] = acc + xa;
        __syncthreads();
        if (t < 256) {
            float iv = gv[t], fv = gv[t + 256], gg = gv[t + 512], ov = gv[t + 768];
            creg = sigf(fv) * creg + sigf(iv) * tanhfast(gg);
            float hv = sigf(ov) * tanhfast(creg);
            if (step == 31) hT[(size_t)(dir * 4 + batch) * 256 + t] = hv;
            float hnext = __shfl_down(hv, 1, 64);
            if ((t & 1) == 0) h_pk[t >> 1] = packh2(hv, hnext);
        }
        __syncthreads();
    }
}

// ---------------- heads: mu/logvar/pi from concat(h_f, h_b) ----------------
__global__ __launch_bounds__(256) void heads_kernel(const float* __restrict__ hT,
                                                    const float* __restrict__ Wmu, const float* __restrict__ bmu,
                                                    const float* __restrict__ Wlv, const float* __restrict__ blv,
                                                    const float* __restrict__ Wpi, const float* __restrict__ bpi,
                                                    float* __restrict__ out) {
    __shared__ __align__(16) float feat[4][512];
    int tid = threadIdx.x;
    for (int i = tid; i < 2048; i += 256) {
        int b = i >> 9, j = i & 511;
        int d = j >> 8, jj = j & 255;
        feat[b][j] = hT[(size_t)(d * 4 + b) * 256 + jj];
    }
    __syncthreads();
    int o = blockIdx.x * 256 + tid;
    if (o >= 4128) return;
    const float* Wr;
    float bv;
    int kind, m;
    if (o < 2048) { Wr = Wmu + (size_t)o * 512; bv = bmu[o]; kind = 0; m = o; }
    else if (o < 4096) { m = o - 2048; Wr = Wlv + (size_t)m * 512; bv = blv[m]; kind = 1; }
    else { m = o - 4096; Wr = Wpi + (size_t)m * 512; bv = bpi[m]; kind = 2; }
    float s0 = bv, s1 = bv, s2 = bv, s3 = bv;
    for (int k = 0; k < 512; k += 4) {
        float4 wv = *(const float4*)(Wr + k);
        s0 += feat[0][k] * wv.x + feat[0][k + 1] * wv.y + feat[0][k + 2] * wv.z + feat[0][k + 3] * wv.w;
        s1 += feat[1][k] * wv.x + feat[1][k + 1] * wv.y + feat[1][k + 2] * wv.z + feat[1][k + 3] * wv.w;
        s2 += feat[2][k] * wv.x + feat[2][k + 1] * wv.y + feat[2][k + 2] * wv.z + feat[2][k + 3] * wv.w;
        s3 += feat[3][k] * wv.x + feat[3][k + 1] * wv.y + feat[3][k + 2] * wv.z + feat[3][k + 3] * wv.w;
    }
    if (kind == 0) {
        out[0 * 2048 + m] = s0; out[1 * 2048 + m] = s1; out[2 * 2048 + m] = s2; out[3 * 2048 + m] = s3;
    } else if (kind == 1) {
        out[8192 + 0 * 2048 + m] = s0; out[8192 + 1 * 2048 + m] = s1;
        out[8192 + 2 * 2048 + m] = s2; out[8192 + 3 * 2048 + m] = s3;
    } else {
        out[16384 + 0 * 32 + m] = s0; out[16384 + 1 * 32 + m] = s1;
        out[16384 + 2 * 32 + m] = s2; out[16384 + 3 * 32 + m] = s3;
    }
}

extern "C" void kernel_launch(void* const* d_in, const int* in_sizes, int n_in,
                              void* d_out, int out_size, void* d_ws, size_t ws_size,
                              hipStream_t stream) {
    const float* x = (const float*)d_in[0];
    const int* ei = (const int*)d_in[1];
    const float* W1 = (const float*)d_in[2];
    const float* as1 = (const float*)d_in[3];
    const float* ad1 = (const float*)d_in[4];
    const float* b1 = (const float*)d_in[5];
    const float* W2 = (const float*)d_in[6];
    const float* as2 = (const float*)d_in[7];
    const float* ad2 = (const float*)d_in[8];
    const float* b2 = (const float*)d_in[9];
    const float* W3 = (const float*)d_in[10];
    const float* as3 = (const float*)d_in[11];
    const float* ad3 = (const float*)d_in[12];
    const float* b3 = (const float*)d_in[13];
    const float* Wih_f = (const float*)d_in[14];
    const float* Whh_f = (const float*)d_in[15];
    const float* bih_f = (const float*)d_in[16];
    const float* bhh_f = (const float*)d_in[17];
    const float* Wih_b = (const float*)d_in[18];
    const float* Whh_b = (const float*)d_in[19];
    const float* bih_b = (const float*)d_in[20];
    const float* bhh_b = (const float*)d_in[21];
    const float* Wmu = (const float*)d_in[22];
    const float* bmu = (const float*)d_in[23];
    const float* Wlv = (const float*)d_in[24];
    const float* blv = (const float*)d_in[25];
    const float* Wpi = (const float*)d_in[26];
    const float* bpi = (const float*)d_in[27];

    float* ws = (float*)d_ws;
    float* bufA = ws;                    // 4,194,304 f32 (feature buffer)
    float* bufB = ws + 4194304;          // 4,194,304 f32 (output buffer)
    int* cnt = (int*)(ws + 8519680);     // 128 ints
    int* col = cnt + 128;                // 32,768 ints
    float* xp = ws + 8560768;            // 262,144
    float* hT = ws + 8822912;            // 2,048 (final h per dir x batch)
    uint32_t* wreg = (uint32_t*)ws;      // 196,608 u32 — overlaps bufA (dead by then)
    uint32_t* wtail = wreg + 196608;     // 65,536 u32
    float* out = (float*)d_out;

    build_csr_kernel<<<128, 256, 0, stream>>>(ei, cnt, col);

    // GAT layer 1 (att fused into agg)
    gemm128_kernel<<<dim3(2, 128), 256, 0, stream>>>(x, W1, bufA, NNODE, 256, 64);
    agg_kernel<4><<<128, 512, 0, stream>>>(bufA, as1, ad1, cnt, col, b1, bufB);
    // GAT layer 2
    gemm128_kernel<<<dim3(2, 128), 256, 0, stream>>>(bufB, W2, bufA, NNODE, 256, 256);
    agg_kernel<4><<<128, 512, 0, stream>>>(bufA, as2, ad2, cnt, col, b2, bufB);
    // GAT layer 3 (single head, N=64)
    gemm_kernel<<<dim3(1, 256), 256, 0, stream>>>(bufB, W3, bufA, NNODE, 64, 256);
    agg_kernel<1><<<128, 512, 0, stream>>>(bufA, as3, ad3, cnt, col, b3, bufB);
    // bufA dead from here on -> wreg/wtail may overwrite its first 1 MB
    wpack_kernel<<<8, 256, 0, stream>>>(Whh_f, Whh_b, wreg, wtail);
    // fused pool+xpart, BiLSTM, heads
    poolx_kernel<<<128, 256, 0, stream>>>(bufB, Wih_f, bih_f, bhh_f, Wih_b, bih_b, bhh_b, xp);
    lstm_kernel<<<8, 1024, 0, stream>>>(xp, wreg, wtail, hT);
    heads_kernel<<<17, 256, 0, stream>>>(hT, Wmu, bmu, Wlv, blv, Wpi, bpi, out);
}

// Round 13
// 301.356 us; speedup vs baseline: 1.4067x; 1.4067x over previous
//
#include <hip/hip_runtime.h>
#include <hip/hip_bf16.h>
#include <cstdint>

#define NLOC 128        // nodes per graph
#define NGRAPH 128      // bs*T
#define NNODE 16384     // total nodes
#define EBASE 2048      // base edges per graph

typedef _Float16 half2v __attribute__((ext_vector_type(2)));
typedef _Float16 f16x8 __attribute__((ext_vector_type(8)));
typedef float f32x4 __attribute__((ext_vector_type(4)));

__device__ __forceinline__ float sigf(float x) { return 1.f / (1.f + __expf(-x)); }
__device__ __forceinline__ float tanhfast(float x) {
    float e = __expf(2.f * x);
    return 1.f - 2.f / (e + 1.f);
}
__device__ __forceinline__ uint32_t packh2(float a, float b) {
    half2v v;
    v.x = (_Float16)a; v.y = (_Float16)b;
    return __builtin_bit_cast(uint32_t, v);
}
__device__ __forceinline__ float dot2(uint32_t w, uint32_t h, float acc) {
#if __has_builtin(__builtin_amdgcn_fdot2)
    return __builtin_amdgcn_fdot2(__builtin_bit_cast(half2v, w),
                                  __builtin_bit_cast(half2v, h), acc, false);
#else
    half2v wv = __builtin_bit_cast(half2v, w);
    half2v hv = __builtin_bit_cast(half2v, h);
    return acc + (float)wv.x * (float)hv.x + (float)wv.y * (float)hv.y;
#endif
}

// ---------------- dense adjacency counts (shared by all graphs): A[v][u] = mult + self ----
__global__ __launch_bounds__(256) void build_adj_kernel(const int* __restrict__ ei,
                                                        float* __restrict__ Adj) {
    __shared__ int rowA[NLOC];
    int v = blockIdx.x, tid = threadIdx.x;
    if (tid < NLOC) rowA[tid] = 0;
    __syncthreads();
    const int* srcs = ei;
    const int* dsts = ei + EBASE;
    int e0 = tid * 8;
#pragma unroll
    for (int k = 0; k < 8; ++k)
        if (dsts[e0 + k] == v) atomicAdd(&rowA[srcs[e0 + k]], 1);
    __syncthreads();
    if (tid < NLOC) Adj[v * NLOC + tid] = (float)rowA[tid] + (tid == v ? 1.f : 0.f);
}

// ---------------- fp32 GEMM 128x128 tile, 8x8 micro-tile ----------------
__global__ __launch_bounds__(256) void gemm128_kernel(const float* __restrict__ A,
                                                      const float* __restrict__ B,
                                                      float* __restrict__ C,
                                                      int M, int N, int K) {
    __shared__ __align__(16) float As[16][128];   // [k][m]
    __shared__ __align__(16) float Bs[16][128];   // [k][n]
    int tid = threadIdx.x;
    int bm = blockIdx.y, bn = blockIdx.x;
    int ar = tid >> 1, ak = (tid & 1) * 8;
    int bk = tid >> 4, bc = (tid & 15) * 8;
    int ty = tid >> 4, tx = tid & 15;
    const float* Ab = A + (size_t)(bm * 128 + ar) * K;
    const float* Bb = B + (size_t)bn * 128 + bc;
    float acc[8][8] = {};
    for (int k0 = 0; k0 < K; k0 += 16) {
        float4 a0 = *(const float4*)(Ab + k0 + ak);
        float4 a1 = *(const float4*)(Ab + k0 + ak + 4);
        float4 b0 = *(const float4*)(Bb + (size_t)(k0 + bk) * N);
        float4 b1 = *(const float4*)(Bb + (size_t)(k0 + bk) * N + 4);
        As[ak + 0][ar] = a0.x; As[ak + 1][ar] = a0.y; As[ak + 2][ar] = a0.z; As[ak + 3][ar] = a0.w;
        As[ak + 4][ar] = a1.x; As[ak + 5][ar] = a1.y; As[ak + 6][ar] = a1.z; As[ak + 7][ar] = a1.w;
        *(float4*)&Bs[bk][bc] = b0;
        *(float4*)&Bs[bk][bc + 4] = b1;
        __syncthreads();
#pragma unroll
        for (int kk = 0; kk < 16; ++kk) {
            float4 x0 = *(const float4*)&As[kk][ty * 8];
            float4 x1 = *(const float4*)&As[kk][ty * 8 + 4];
            float4 y0 = *(const float4*)&Bs[kk][tx * 8];
            float4 y1 = *(const float4*)&Bs[kk][tx * 8 + 4];
            float xa[8] = {x0.x, x0.y, x0.z, x0.w, x1.x, x1.y, x1.z, x1.w};
            float yb[8] = {y0.x, y0.y, y0.z, y0.w, y1.x, y1.y, y1.z, y1.w};
#pragma unroll
            for (int i = 0; i < 8; ++i)
#pragma unroll
                for (int j = 0; j < 8; ++j) acc[i][j] += xa[i] * yb[j];
        }
        __syncthreads();
    }
    float* Cb = C + (size_t)(bm * 128 + ty * 8) * N + (size_t)bn * 128 + tx * 8;
#pragma unroll
    for (int i = 0; i < 8; ++i) {
        *(float4*)(Cb + (size_t)i * N) = make_float4(acc[i][0], acc[i][1], acc[i][2], acc[i][3]);
        *(float4*)(Cb + (size_t)i * N + 4) = make_float4(acc[i][4], acc[i][5], acc[i][6], acc[i][7]);
    }
}

// ---------------- fp32 tiled GEMM 64x64 (N=64 layer-3) ----------------
__global__ __launch_bounds__(256) void gemm_kernel(const float* __restrict__ A,
                                                   const float* __restrict__ B,
                                                   float* __restrict__ C,
                                                   int M, int N, int K) {
    __shared__ __align__(16) float As[16][64];
    __shared__ __align__(16) float Bs[16][64];
    int tid = threadIdx.x;
    int bm = blockIdx.y, bn = blockIdx.x;
    int am = tid >> 2, ak = (tid & 3) << 2;
    int bk = tid >> 4, bn4 = (tid & 15) << 2;
    int ty = tid >> 4, tx = tid & 15;
    const float* Ab = A + (size_t)bm * 64 * K;
    const float* Bb = B + bn * 64;
    float acc[4][4] = {};
    for (int k0 = 0; k0 < K; k0 += 16) {
        float4 av = *(const float4*)(Ab + (size_t)am * K + k0 + ak);
        float4 bv = *(const float4*)(Bb + (size_t)(k0 + bk) * N + bn4);
        As[ak + 0][am] = av.x; As[ak + 1][am] = av.y;
        As[ak + 2][am] = av.z; As[ak + 3][am] = av.w;
        *(float4*)&Bs[bk][bn4] = bv;
        __syncthreads();
#pragma unroll
        for (int kk = 0; kk < 16; ++kk) {
            float4 a4 = *(const float4*)&As[kk][ty << 2];
            float4 b4 = *(const float4*)&Bs[kk][tx << 2];
            acc[0][0] += a4.x * b4.x; acc[0][1] += a4.x * b4.y; acc[0][2] += a4.x * b4.z; acc[0][3] += a4.x * b4.w;
            acc[1][0] += a4.y * b4.x; acc[1][1] += a4.y * b4.y; acc[1][2] += a4.y * b4.z; acc[1][3] += a4.y * b4.w;
            acc[2][0] += a4.z * b4.x; acc[2][1] += a4.z * b4.y; acc[2][2] += a4.z * b4.z; acc[2][3] += a4.z * b4.w;
            acc[3][0] += a4.w * b4.x; acc[3][1] += a4.w * b4.y; acc[3][2] += a4.w * b4.z; acc[3][3] += a4.w * b4.w;
        }
        __syncthreads();
    }
    float* Cb = C + (size_t)(bm * 64 + ty * 4) * N + bn * 64 + tx * 4;
#pragma unroll
    for (int i = 0; i < 4; ++i)
        *(float4*)(Cb + (size_t)i * N) = make_float4(acc[i][0], acc[i][1], acc[i][2], acc[i][3]);
}

// ---------------- GAT aggregation v6: dense per-graph MFMA --------------------------------
// Per block (graph): out_h = alpha_h(128x128) @ H_h(128x64) per head via
// v_mfma_f32_16x16x32_f16, fp32 accum. W_h[v][u] = A[v][u]*exp(leaky(as_u+ad_v)) (f16),
// den fp32. Ht = f16 transposed [f][u] (B^T form); fragments: lane row = l&15, 8 contiguous
// k at (l>>4)*8 (m97-verified pattern); C/D col=l&15,row=(l>>4)*4+r. Heads sequential so
// one 35KB W buffer is reused; removes ALL dependent gather loads (R12: agg = 93us,
// 393K bank conflicts, latency-bound).
template <int F>
__global__ __launch_bounds__(512) void aggm_kernel(const float* __restrict__ hf,
                                                   const float* __restrict__ a_s,
                                                   const float* __restrict__ a_d,
                                                   const float* __restrict__ Adj,
                                                   const float* __restrict__ bias,
                                                   float* __restrict__ out) {
    constexpr int H = F / 64;
    constexpr int LDH = 136;                     // f16 row stride (272B, 16B-aligned, +8 pad)
    __shared__ _Float16 Wt[128 * LDH];           // 34.8 KB, rebuilt per head
    __shared__ _Float16 Ht[F * LDH];             // 69.6 KB (F=256) / 17.4 KB (F=64)
    __shared__ float as_l[128 * H];
    __shared__ float ad_l[128 * H];
    __shared__ float den_l[128];
    int g = blockIdx.x, tid = threadIdx.x;
    int lane = tid & 63, w = tid >> 6;           // 8 waves
    int base = g * 128;
    // ---- stage: H -> f16 transposed Ht[f][u]; fused as/ad dots (same shfl tree as before)
    for (int np = w; np < 64; np += 8) {
        int n0 = 2 * np, n1 = n0 + 1;
#pragma unroll
        for (int r = 0; r < H; ++r) {
            int f = r * 64 + lane;
            float v0 = hf[(size_t)(base + n0) * F + f];
            float v1 = hf[(size_t)(base + n1) * F + f];
            *(uint32_t*)&Ht[f * LDH + n0] = packh2(v0, v1);
            float ps0 = v0 * a_s[f], pd0 = v0 * a_d[f];
            float ps1 = v1 * a_s[f], pd1 = v1 * a_d[f];
#pragma unroll
            for (int off = 32; off > 0; off >>= 1) {
                ps0 += __shfl_xor(ps0, off, 64);
                pd0 += __shfl_xor(pd0, off, 64);
                ps1 += __shfl_xor(ps1, off, 64);
                pd1 += __shfl_xor(pd1, off, 64);
            }
            if (lane == 0) {
                as_l[n0 * H + r] = ps0; ad_l[n0 * H + r] = pd0;
                as_l[n1 * H + r] = ps1; ad_l[n1 * H + r] = pd1;
            }
        }
    }
    __syncthreads();
    int col = lane & 15, kg = lane >> 4;
    for (int h = 0; h < H; ++h) {
        // ---- W_h build: thread (v, 32-u block); den row-sum fp32 via quad shfl
        {
            int v = tid >> 2, ub = (tid & 3) * 32;
            float advv = ad_l[v * H + h];
            const float* arow = Adj + (size_t)v * 128 + ub;
            float dsum = 0.f;
#pragma unroll
            for (int j = 0; j < 16; ++j) {
                float a0 = arow[2 * j], a1 = arow[2 * j + 1];
                float e0 = as_l[(ub + 2 * j) * H + h] + advv;
                float e1 = as_l[(ub + 2 * j + 1) * H + h] + advv;
                e0 = (e0 > 0.f) ? e0 : 0.2f * e0;
                e1 = (e1 > 0.f) ? e1 : 0.2f * e1;
                float w0 = a0 * __expf(e0);
                float w1 = a1 * __expf(e1);
                dsum += w0 + w1;
                *(uint32_t*)&Wt[v * LDH + ub + 2 * j] = packh2(w0, w1);
            }
            dsum += __shfl_xor(dsum, 1, 64);
            dsum += __shfl_xor(dsum, 2, 64);
            if ((tid & 3) == 0) den_l[v] = dsum;
        }
        __syncthreads();
        // ---- MFMA: wave w owns vt=w; 4 f-tiles of this head
        {
            int vt = w;
            f16x8 af[4];
#pragma unroll
            for (int kt = 0; kt < 4; ++kt) {
                uint4 au = *(const uint4*)&Wt[(vt * 16 + col) * LDH + kt * 32 + kg * 8];
                af[kt] = __builtin_bit_cast(f16x8, au);
            }
            float dn[4];
#pragma unroll
            for (int r = 0; r < 4; ++r) dn[r] = den_l[vt * 16 + kg * 4 + r] + 1e-16f;
#pragma unroll
            for (int ft = 0; ft < 4; ++ft) {
                int f = h * 64 + ft * 16 + col;
                f32x4 acc = {0.f, 0.f, 0.f, 0.f};
#pragma unroll
                for (int kt = 0; kt < 4; ++kt) {
                    uint4 bu = *(const uint4*)&Ht[f * LDH + kt * 32 + kg * 8];
                    f16x8 bf = __builtin_bit_cast(f16x8, bu);
                    acc = __builtin_amdgcn_mfma_f32_16x16x32_f16(af[kt], bf, acc, 0, 0, 0);
                }
                float bv = bias[f];
#pragma unroll
                for (int r = 0; r < 4; ++r) {
                    int v = vt * 16 + kg * 4 + r;
                    float o = acc[r] / dn[r] + bv;
                    out[(size_t)(base + v) * F + f] = fmaxf(o, 0.f);
                }
            }
        }
        __syncthreads();
    }
}

// ---------------- fused pool + LSTM input part --------------------------------------------
__global__ __launch_bounds__(256) void poolx_kernel(const float* __restrict__ h,
                                                    const float* __restrict__ Wf, const float* __restrict__ bif, const float* __restrict__ bhf,
                                                    const float* __restrict__ Wb, const float* __restrict__ bib, const float* __restrict__ bhb,
                                                    float* __restrict__ xp) {
    __shared__ float part_l[4][64];
    __shared__ float emb[64];
    int g = blockIdx.x, tid = threadIdx.x;
    int c = tid & 63, prt = tid >> 6;
    {
        const float* p = h + (size_t)g * 8192 + prt * 32 * 64 + c;
        float s = 0.f;
#pragma unroll
        for (int vv = 0; vv < 32; ++vv) s += p[vv * 64];
        part_l[prt][c] = s;
    }
    __syncthreads();
    if (tid < 64) emb[tid] = part_l[0][tid] + part_l[1][tid] + part_l[2][tid] + part_l[3][tid];
    __syncthreads();
    int r = (g & 31) * 4 + (g >> 5);
    for (int dir = 0; dir < 2; ++dir) {
        const float* W = dir ? Wb : Wf;
        const float* bi = dir ? bib : bif;
        const float* bh = dir ? bhb : bhf;
        for (int o = tid; o < 1024; o += 256) {
            const float* wr = W + (size_t)o * 64;
            float s = bi[o] + bh[o];
#pragma unroll
            for (int k = 0; k < 64; k += 4) {
                float4 wv = *(const float4*)(wr + k);
                s += emb[k] * wv.x + emb[k + 1] * wv.y + emb[k + 2] * wv.z + emb[k + 3] * wv.w;
            }
            xp[dir * 131072 + r * 1024 + o] = s;
        }
    }
}

// ---------------- pre-pack Whh to f16 pairs (v7 layout) ----------------------------------
__global__ __launch_bounds__(256) void wpack_kernel(const float* __restrict__ Whh_f,
                                                    const float* __restrict__ Whh_b,
                                                    uint32_t* __restrict__ wreg,
                                                    uint32_t* __restrict__ wtail) {
    int gid = blockIdx.x * 256 + threadIdx.x;   // 0..2047
    int dir = gid >> 10, row = gid & 1023;
    const float* src = (dir ? Whh_b : Whh_f) + (size_t)row * 256;
    uint4* wr4 = (uint4*)wreg;
#pragma unroll
    for (int i = 0; i < 24; ++i) {
        uint4 v;
        v.x = packh2(src[i * 8 + 0], src[i * 8 + 1]);
        v.y = packh2(src[i * 8 + 2], src[i * 8 + 3]);
        v.z = packh2(src[i * 8 + 4], src[i * 8 + 5]);
        v.w = packh2(src[i * 8 + 6], src[i * 8 + 7]);
        wr4[(size_t)(dir * 24 + i) * 1024 + row] = v;
    }
    uint4* wt4 = (uint4*)wtail;
#pragma unroll
    for (int ku = 0; ku < 8; ++ku) {
        const float* s8 = src + 192 + ku * 8;
        uint4 v;
        v.x = packh2(s8[0], s8[1]);
        v.y = packh2(s8[2], s8[3]);
        v.z = packh2(s8[4], s8[5]);
        v.w = packh2(s8[6], s8[7]);
        wt4[(size_t)(dir * 8 + ku) * 1024 + row] = v;
    }
}

// ---------------- BiLSTM recurrent v7 (kept from R12) -------------------------------------
__global__ __launch_bounds__(1024, 1) void lstm_kernel(const float* __restrict__ xp,
                                                       const uint32_t* __restrict__ wreg,
                                                       const uint32_t* __restrict__ wtail,
                                                       float* __restrict__ hT) {
    int blk = blockIdx.x;
    int dir = blk >> 2, batch = blk & 3;
    int t = threadIdx.x;                      // gate row 0..1023
    uint32_t wa[96];
    {
        const uint4* ra = (const uint4*)wreg + (size_t)dir * 24 * 1024;
#pragma unroll
        for (int i = 0; i < 24; ++i) {
            uint4 v = ra[i * 1024 + t];
            wa[i * 4 + 0] = v.x; wa[i * 4 + 1] = v.y; wa[i * 4 + 2] = v.z; wa[i * 4 + 3] = v.w;
        }
    }
    __shared__ __align__(16) uint4 wlds[8 * 1024];   // 128 KB tail, [ku][row]
    __shared__ __align__(16) uint32_t h_pk[128];     // h as 128 half2 pairs
    __shared__ float gv[1024];
    {
        const uint4* tsrc = (const uint4*)wtail + (size_t)dir * 8 * 1024;
        for (int i = t; i < 8 * 1024; i += 1024) wlds[i] = tsrc[i];
    }
    if (t < 128) h_pk[t] = 0;
    __syncthreads();
    float creg = 0.f;
    const float* xpb = xp + dir * 131072 + batch * 1024;
#pragma unroll 1
    for (int step = 0; step < 32; ++step) {
        int teff = dir ? (31 - step) : step;
        float xa = xpb[teff * 4096 + t];
        float acc = 0.f;
#pragma unroll
        for (int q = 0; q < 24; ++q) {
            uint4 hq = *(const uint4*)&h_pk[q * 4];   // same-address broadcast b128
            acc = dot2(wa[q * 4 + 0], hq.x, acc);
            acc = dot2(wa[q * 4 + 1], hq.y, acc);
            acc = dot2(wa[q * 4 + 2], hq.z, acc);
            acc = dot2(wa[q * 4 + 3], hq.w, acc);
        }
#pragma unroll
        for (int ku = 0; ku < 8; ++ku) {
            uint4 hq = *(const uint4*)&h_pk[96 + ku * 4];  // broadcast b128
            uint4 qa = wlds[ku * 1024 + t];                // conflict-free b128
            acc = dot2(qa.x, hq.x, acc); acc = dot2(qa.y, hq.y, acc);
            acc = dot2(qa.z, hq.z, acc); acc = dot2(qa.w, hq.w, acc);
        }
        gv[t] = acc + xa;
        __syncthreads();
        if (t < 256) {
            float iv = gv[t], fv = gv[t + 256], gg = gv[t + 512], ov = gv[t + 768];
            creg = sigf(fv) * creg + sigf(iv) * tanhfast(gg);
            float hv = sigf(ov) * tanhfast(creg);
            if (step == 31) hT[(size_t)(dir * 4 + batch) * 256 + t] = hv;
            float hnext = __shfl_down(hv, 1, 64);
            if ((t & 1) == 0) h_pk[t >> 1] = packh2(hv, hnext);
        }
        __syncthreads();
    }
}

// ---------------- heads: mu/logvar/pi from concat(h_f, h_b) ----------------
__global__ __launch_bounds__(256) void heads_kernel(const float* __restrict__ hT,
                                                    const float* __restrict__ Wmu, const float* __restrict__ bmu,
                                                    const float* __restrict__ Wlv, const float* __restrict__ blv,
                                                    const float* __restrict__ Wpi, const float* __restrict__ bpi,
                                                    float* __restrict__ out) {
    __shared__ __align__(16) float feat[4][512];
    int tid = threadIdx.x;
    for (int i = tid; i < 2048; i += 256) {
        int b = i >> 9, j = i & 511;
        int d = j >> 8, jj = j & 255;
        feat[b][j] = hT[(size_t)(d * 4 + b) * 256 + jj];
    }
    __syncthreads();
    int o = blockIdx.x * 256 + tid;
    if (o >= 4128) return;
    const float* Wr;
    float bv;
    int kind, m;
    if (o < 2048) { Wr = Wmu + (size_t)o * 512; bv = bmu[o]; kind = 0; m = o; }
    else if (o < 4096) { m = o - 2048; Wr = Wlv + (size_t)m * 512; bv = blv[m]; kind = 1; }
    else { m = o - 4096; Wr = Wpi + (size_t)m * 512; bv = bpi[m]; kind = 2; }
    float s0 = bv, s1 = bv, s2 = bv, s3 = bv;
    for (int k = 0; k < 512; k += 4) {
        float4 wv = *(const float4*)(Wr + k);
        s0 += feat[0][k] * wv.x + feat[0][k + 1] * wv.y + feat[0][k + 2] * wv.z + feat[0][k + 3] * wv.w;
        s1 += feat[1][k] * wv.x + feat[1][k + 1] * wv.y + feat[1][k + 2] * wv.z + feat[1][k + 3] * wv.w;
        s2 += feat[2][k] * wv.x + feat[2][k + 1] * wv.y + feat[2][k + 2] * wv.z + feat[2][k + 3] * wv.w;
        s3 += feat[3][k] * wv.x + feat[3][k + 1] * wv.y + feat[3][k + 2] * wv.z + feat[3][k + 3] * wv.w;
    }
    if (kind == 0) {
        out[0 * 2048 + m] = s0; out[1 * 2048 + m] = s1; out[2 * 2048 + m] = s2; out[3 * 2048 + m] = s3;
    } else if (kind == 1) {
        out[8192 + 0 * 2048 + m] = s0; out[8192 + 1 * 2048 + m] = s1;
        out[8192 + 2 * 2048 + m] = s2; out[8192 + 3 * 2048 + m] = s3;
    } else {
        out[16384 + 0 * 32 + m] = s0; out[16384 + 1 * 32 + m] = s1;
        out[16384 + 2 * 32 + m] = s2; out[16384 + 3 * 32 + m] = s3;
    }
}

extern "C" void kernel_launch(void* const* d_in, const int* in_sizes, int n_in,
                              void* d_out, int out_size, void* d_ws, size_t ws_size,
                              hipStream_t stream) {
    const float* x = (const float*)d_in[0];
    const int* ei = (const int*)d_in[1];
    const float* W1 = (const float*)d_in[2];
    const float* as1 = (const float*)d_in[3];
    const float* ad1 = (const float*)d_in[4];
    const float* b1 = (const float*)d_in[5];
    const float* W2 = (const float*)d_in[6];
    const float* as2 = (const float*)d_in[7];
    const float* ad2 = (const float*)d_in[8];
    const float* b2 = (const float*)d_in[9];
    const float* W3 = (const float*)d_in[10];
    const float* as3 = (const float*)d_in[11];
    const float* ad3 = (const float*)d_in[12];
    const float* b3 = (const float*)d_in[13];
    const float* Wih_f = (const float*)d_in[14];
    const float* Whh_f = (const float*)d_in[15];
    const float* bih_f = (const float*)d_in[16];
    const float* bhh_f = (const float*)d_in[17];
    const float* Wih_b = (const float*)d_in[18];
    const float* Whh_b = (const float*)d_in[19];
    const float* bih_b = (const float*)d_in[20];
    const float* bhh_b = (const float*)d_in[21];
    const float* Wmu = (const float*)d_in[22];
    const float* bmu = (const float*)d_in[23];
    const float* Wlv = (const float*)d_in[24];
    const float* blv = (const float*)d_in[25];
    const float* Wpi = (const float*)d_in[26];
    const float* bpi = (const float*)d_in[27];

    float* ws = (float*)d_ws;
    float* bufA = ws;                    // 4,194,304 f32 (feature buffer)
    float* bufB = ws + 4194304;          // 4,194,304 f32 (output buffer)
    float* Adj = ws + 8519680;           // 16,384 f32 dense adjacency counts
    float* xp = ws + 8560768;            // 262,144
    float* hT = ws + 8822912;            // 2,048 (final h per dir x batch)
    uint32_t* wreg = (uint32_t*)ws;      // 196,608 u32 — overlaps bufA (dead by then)
    uint32_t* wtail = wreg + 196608;     // 65,536 u32
    float* out = (float*)d_out;

    build_adj_kernel<<<128, 256, 0, stream>>>(ei, Adj);

    // GAT layer 1 (att fused into aggm)
    gemm128_kernel<<<dim3(2, 128), 256, 0, stream>>>(x, W1, bufA, NNODE, 256, 64);
    aggm_kernel<256><<<128, 512, 0, stream>>>(bufA, as1, ad1, Adj, b1, bufB);
    // GAT layer 2
    gemm128_kernel<<<dim3(2, 128), 256, 0, stream>>>(bufB, W2, bufA, NNODE, 256, 256);
    aggm_kernel<256><<<128, 512, 0, stream>>>(bufA, as2, ad2, Adj, b2, bufB);
    // GAT layer 3 (single head, 64 features)
    gemm_kernel<<<dim3(1, 256), 256, 0, stream>>>(bufB, W3, bufA, NNODE, 64, 256);
    aggm_kernel<64><<<128, 512, 0, stream>>>(bufA, as3, ad3, Adj, b3, bufB);
    // bufA dead from here on -> wreg/wtail may overwrite its first 1 MB
    wpack_kernel<<<8, 256, 0, stream>>>(Whh_f, Whh_b, wreg, wtail);
    // fused pool+xpart, BiLSTM, heads
    poolx_kernel<<<128, 256, 0, stream>>>(bufB, Wih_f, bih_f, bhh_f, Wih_b, bih_b, bhh_b, xp);
    lstm_kernel<<<8, 1024, 0, stream>>>(xp, wreg, wtail, hT);
    heads_kernel<<<17, 256, 0, stream>>>(hT, Wmu, bmu, Wlv, blv, Wpi, bpi, out);
}

// Round 14
// 247.933 us; speedup vs baseline: 1.7099x; 1.2155x over previous
//
#include <hip/hip_runtime.h>
#include <hip/hip_bf16.h>
#include <cstdint>

#define NLOC 128        // nodes per graph
#define NGRAPH 128      // bs*T
#define NNODE 16384     // total nodes
#define EBASE 2048      // base edges per graph

typedef _Float16 half2v __attribute__((ext_vector_type(2)));
typedef _Float16 f16x8 __attribute__((ext_vector_type(8)));
typedef float f32x4 __attribute__((ext_vector_type(4)));

__device__ __forceinline__ float sigf(float x) { return 1.f / (1.f + __expf(-x)); }
__device__ __forceinline__ float tanhfast(float x) {
    float e = __expf(2.f * x);
    return 1.f - 2.f / (e + 1.f);
}
__device__ __forceinline__ uint32_t packh2(float a, float b) {
    half2v v;
    v.x = (_Float16)a; v.y = (_Float16)b;
    return __builtin_bit_cast(uint32_t, v);
}
__device__ __forceinline__ float dot2(uint32_t w, uint32_t h, float acc) {
#if __has_builtin(__builtin_amdgcn_fdot2)
    return __builtin_amdgcn_fdot2(__builtin_bit_cast(half2v, w),
                                  __builtin_bit_cast(half2v, h), acc, false);
#else
    half2v wv = __builtin_bit_cast(half2v, w);
    half2v hv = __builtin_bit_cast(half2v, h);
    return acc + (float)wv.x * (float)hv.x + (float)wv.y * (float)hv.y;
#endif
}

// ---------------- prep: dense adjacency + f16-transposed GAT weights ----------------------
// blocks 0..127: Adj[v][u] = edge multiplicity + self-loop (shared by all graphs)
// blocks 128..143: W1t[256n][64k]; 144..207: W2t[256n][256k]; 208..223: W3t[64n][256k]
__global__ __launch_bounds__(256) void prep_kernel(const int* __restrict__ ei,
                                                   float* __restrict__ Adj,
                                                   const float* __restrict__ W1,
                                                   const float* __restrict__ W2,
                                                   const float* __restrict__ W3,
                                                   _Float16* __restrict__ W1t,
                                                   _Float16* __restrict__ W2t,
                                                   _Float16* __restrict__ W3t) {
    int b = blockIdx.x, tid = threadIdx.x;
    if (b < 128) {
        __shared__ int rowA[NLOC];
        int v = b;
        if (tid < NLOC) rowA[tid] = 0;
        __syncthreads();
        const int* srcs = ei;
        const int* dsts = ei + EBASE;
        int e0 = tid * 8;
#pragma unroll
        for (int k = 0; k < 8; ++k)
            if (dsts[e0 + k] == v) atomicAdd(&rowA[srcs[e0 + k]], 1);
        __syncthreads();
        if (tid < NLOC) Adj[v * NLOC + tid] = (float)rowA[tid] + (tid == v ? 1.f : 0.f);
    } else if (b < 144) {
        int i = (b - 128) * 1024 + tid * 4;
        int n = i >> 6, k = i & 63;
#pragma unroll
        for (int j = 0; j < 4; ++j) W1t[n * 64 + k + j] = (_Float16)W1[(size_t)(k + j) * 256 + n];
    } else if (b < 208) {
        int i = (b - 144) * 1024 + tid * 4;
        int n = i >> 8, k = i & 255;
#pragma unroll
        for (int j = 0; j < 4; ++j) W2t[n * 256 + k + j] = (_Float16)W2[(size_t)(k + j) * 256 + n];
    } else {
        int i = (b - 208) * 1024 + tid * 4;
        int n = i >> 8, k = i & 255;
#pragma unroll
        for (int j = 0; j < 4; ++j) W3t[n * 256 + k + j] = (_Float16)W3[(size_t)(k + j) * 64 + n];
    }
}

// ---------------- f16 MFMA GEMM: C[g*128+m][N] = A[g*128+m][K] @ W[K][N] ------------------
// Per-graph block (128 rows); Wt pre-transposed [n][k] f16 (same B-operand form as aggm's Ht,
// verified R13). Wave grid 2m x 4n; A f16-packed in LDS (pad 4 -> conflict-free b128);
// B staged per-64k chunk in LDS. MTP m-tiles per pass caps acc regs (N=256: 2 passes).
template <int N, int K>
__global__ __launch_bounds__(512) void gemm_mfma_kernel(const float* __restrict__ A,
                                                        const _Float16* __restrict__ Wt,
                                                        float* __restrict__ C) {
    constexpr int LDA = K + 4;
    constexpr int LDB = 68;
    constexpr int NT = N / 64;
    constexpr int MTP = (N == 256) ? 2 : 4;
    constexpr int NPASS = 4 / MTP;
    __shared__ _Float16 As[128 * LDA];
    __shared__ _Float16 Bs[N * LDB];
    int g = blockIdx.x, tid = threadIdx.x;
    int lane = tid & 63, w = tid >> 6;
    int wm = w >> 2, wn = w & 3;
    int col = lane & 15, kg = lane >> 4;
    size_t base = (size_t)g * 128;
    {
        const float* src = A + base * K;
        for (int i = tid; i < 128 * K / 2; i += 512) {
            int m = (2 * i) / K, k = (2 * i) % K;
            float2 v = *(const float2*)(src + (size_t)m * K + k);
            *(uint32_t*)&As[m * LDA + k] = packh2(v.x, v.y);
        }
    }
    for (int pass = 0; pass < NPASS; ++pass) {
        f32x4 acc[MTP][NT];
#pragma unroll
        for (int mt = 0; mt < MTP; ++mt)
#pragma unroll
            for (int nt = 0; nt < NT; ++nt) acc[mt][nt] = (f32x4){0.f, 0.f, 0.f, 0.f};
#pragma unroll 1
        for (int kc = 0; kc < K / 64; ++kc) {
            __syncthreads();
            for (int j = tid; j < N * 8; j += 512) {
                int n = j >> 3, ko = (j & 7) * 8;
                *(uint4*)&Bs[n * LDB + ko] = *(const uint4*)&Wt[(size_t)n * K + kc * 64 + ko];
            }
            __syncthreads();
            uint4 bf[NT][2];
#pragma unroll
            for (int nt = 0; nt < NT; ++nt) {
                int nb = (wn * NT + nt) * 16 + col;
                bf[nt][0] = *(const uint4*)&Bs[nb * LDB + kg * 8];
                bf[nt][1] = *(const uint4*)&Bs[nb * LDB + 32 + kg * 8];
            }
#pragma unroll
            for (int mt = 0; mt < MTP; ++mt) {
                int mrow = wm * 64 + (pass * MTP + mt) * 16 + col;
                uint4 a0 = *(const uint4*)&As[mrow * LDA + kc * 64 + kg * 8];
                uint4 a1 = *(const uint4*)&As[mrow * LDA + kc * 64 + 32 + kg * 8];
#pragma unroll
                for (int nt = 0; nt < NT; ++nt) {
                    acc[mt][nt] = __builtin_amdgcn_mfma_f32_16x16x32_f16(
                        __builtin_bit_cast(f16x8, a0), __builtin_bit_cast(f16x8, bf[nt][0]),
                        acc[mt][nt], 0, 0, 0);
                    acc[mt][nt] = __builtin_amdgcn_mfma_f32_16x16x32_f16(
                        __builtin_bit_cast(f16x8, a1), __builtin_bit_cast(f16x8, bf[nt][1]),
                        acc[mt][nt], 0, 0, 0);
                }
            }
        }
#pragma unroll
        for (int mt = 0; mt < MTP; ++mt) {
            int mrow = wm * 64 + (pass * MTP + mt) * 16;
#pragma unroll
            for (int nt = 0; nt < NT; ++nt) {
                int nb = (wn * NT + nt) * 16 + col;
#pragma unroll
                for (int r = 0; r < 4; ++r)
                    C[(base + mrow + kg * 4 + r) * N + nb] = acc[mt][nt][r];
            }
        }
    }
}

// ---------------- GAT aggregation v6 (R13-verified): dense per-graph MFMA, H=4 ------------
template <int F>
__global__ __launch_bounds__(512) void aggm_kernel(const float* __restrict__ hf,
                                                   const float* __restrict__ a_s,
                                                   const float* __restrict__ a_d,
                                                   const float* __restrict__ Adj,
                                                   const float* __restrict__ bias,
                                                   float* __restrict__ out) {
    constexpr int H = F / 64;
    constexpr int LDH = 136;
    __shared__ _Float16 Wt[128 * LDH];
    __shared__ _Float16 Ht[F * LDH];
    __shared__ float as_l[128 * H];
    __shared__ float ad_l[128 * H];
    __shared__ float den_l[128];
    int g = blockIdx.x, tid = threadIdx.x;
    int lane = tid & 63, w = tid >> 6;
    int base = g * 128;
    for (int np = w; np < 64; np += 8) {
        int n0 = 2 * np, n1 = n0 + 1;
#pragma unroll
        for (int r = 0; r < H; ++r) {
            int f = r * 64 + lane;
            float v0 = hf[(size_t)(base + n0) * F + f];
            float v1 = hf[(size_t)(base + n1) * F + f];
            *(uint32_t*)&Ht[f * LDH + n0] = packh2(v0, v1);
            float ps0 = v0 * a_s[f], pd0 = v0 * a_d[f];
            float ps1 = v1 * a_s[f], pd1 = v1 * a_d[f];
#pragma unroll
            for (int off = 32; off > 0; off >>= 1) {
                ps0 += __shfl_xor(ps0, off, 64);
                pd0 += __shfl_xor(pd0, off, 64);
                ps1 += __shfl_xor(ps1, off, 64);
                pd1 += __shfl_xor(pd1, off, 64);
            }
            if (lane == 0) {
                as_l[n0 * H + r] = ps0; ad_l[n0 * H + r] = pd0;
                as_l[n1 * H + r] = ps1; ad_l[n1 * H + r] = pd1;
            }
        }
    }
    __syncthreads();
    int col = lane & 15, kg = lane >> 4;
    for (int h = 0; h < H; ++h) {
        {
            int v = tid >> 2, ub = (tid & 3) * 32;
            float advv = ad_l[v * H + h];
            const float* arow = Adj + (size_t)v * 128 + ub;
            float dsum = 0.f;
#pragma unroll
            for (int j = 0; j < 16; ++j) {
                float a0 = arow[2 * j], a1 = arow[2 * j + 1];
                float e0 = as_l[(ub + 2 * j) * H + h] + advv;
                float e1 = as_l[(ub + 2 * j + 1) * H + h] + advv;
                e0 = (e0 > 0.f) ? e0 : 0.2f * e0;
                e1 = (e1 > 0.f) ? e1 : 0.2f * e1;
                float w0 = a0 * __expf(e0);
                float w1 = a1 * __expf(e1);
                dsum += w0 + w1;
                *(uint32_t*)&Wt[v * LDH + ub + 2 * j] = packh2(w0, w1);
            }
            dsum += __shfl_xor(dsum, 1, 64);
            dsum += __shfl_xor(dsum, 2, 64);
            if ((tid & 3) == 0) den_l[v] = dsum;
        }
        __syncthreads();
        {
            int vt = w;
            f16x8 af[4];
#pragma unroll
            for (int kt = 0; kt < 4; ++kt) {
                uint4 au = *(const uint4*)&Wt[(vt * 16 + col) * LDH + kt * 32 + kg * 8];
                af[kt] = __builtin_bit_cast(f16x8, au);
            }
            float dn[4];
#pragma unroll
            for (int r = 0; r < 4; ++r) dn[r] = den_l[vt * 16 + kg * 4 + r] + 1e-16f;
#pragma unroll
            for (int ft = 0; ft < 4; ++ft) {
                int f = h * 64 + ft * 16 + col;
                f32x4 acc = {0.f, 0.f, 0.f, 0.f};
#pragma unroll
                for (int kt = 0; kt < 4; ++kt) {
                    uint4 bu = *(const uint4*)&Ht[f * LDH + kt * 32 + kg * 8];
                    f16x8 bfr = __builtin_bit_cast(f16x8, bu);
                    acc = __builtin_amdgcn_mfma_f32_16x16x32_f16(af[kt], bfr, acc, 0, 0, 0);
                }
                float bv = bias[f];
#pragma unroll
                for (int r = 0; r < 4; ++r) {
                    int v = vt * 16 + kg * 4 + r;
                    float o = acc[r] / dn[r] + bv;
                    out[(size_t)(base + v) * F + f] = fmaxf(o, 0.f);
                }
            }
        }
        __syncthreads();
    }
}

// ---------------- aggp: layer-3 agg (H=1) + graph pool + LSTM input part, fused -----------
// Same MFMA structure as aggm<64>, but output never hits global: pool-sum via shfl over
// the accumulators -> emb[64] -> xp rows (removes poolx dispatch + 8MB of bufB traffic).
__global__ __launch_bounds__(512) void aggp_kernel(const float* __restrict__ hf,
                                                   const float* __restrict__ a_s,
                                                   const float* __restrict__ a_d,
                                                   const float* __restrict__ Adj,
                                                   const float* __restrict__ bias,
                                                   const float* __restrict__ Wih_f, const float* __restrict__ bif, const float* __restrict__ bhf,
                                                   const float* __restrict__ Wih_b, const float* __restrict__ bib, const float* __restrict__ bhb,
                                                   float* __restrict__ xp) {
    constexpr int LDH = 136;
    __shared__ _Float16 Wt[128 * LDH];
    __shared__ _Float16 Ht[64 * LDH];
    __shared__ float as_l[128];
    __shared__ float ad_l[128];
    __shared__ float den_l[128];
    __shared__ float psum[8][64];
    __shared__ float emb[64];
    int g = blockIdx.x, tid = threadIdx.x;
    int lane = tid & 63, w = tid >> 6;
    int base = g * 128;
    for (int np = w; np < 64; np += 8) {
        int n0 = 2 * np, n1 = n0 + 1;
        int f = lane;
        float v0 = hf[(size_t)(base + n0) * 64 + f];
        float v1 = hf[(size_t)(base + n1) * 64 + f];
        *(uint32_t*)&Ht[f * LDH + n0] = packh2(v0, v1);
        float ps0 = v0 * a_s[f], pd0 = v0 * a_d[f];
        float ps1 = v1 * a_s[f], pd1 = v1 * a_d[f];
#pragma unroll
        for (int off = 32; off > 0; off >>= 1) {
            ps0 += __shfl_xor(ps0, off, 64);
            pd0 += __shfl_xor(pd0, off, 64);
            ps1 += __shfl_xor(ps1, off, 64);
            pd1 += __shfl_xor(pd1, off, 64);
        }
        if (lane == 0) {
            as_l[n0] = ps0; ad_l[n0] = pd0;
            as_l[n1] = ps1; ad_l[n1] = pd1;
        }
    }
    __syncthreads();
    int col = lane & 15, kg = lane >> 4;
    {
        int v = tid >> 2, ub = (tid & 3) * 32;
        float advv = ad_l[v];
        const float* arow = Adj + (size_t)v * 128 + ub;
        float dsum = 0.f;
#pragma unroll
        for (int j = 0; j < 16; ++j) {
            float a0 = arow[2 * j], a1 = arow[2 * j + 1];
            float e0 = as_l[ub + 2 * j] + advv;
            float e1 = as_l[ub + 2 * j + 1] + advv;
            e0 = (e0 > 0.f) ? e0 : 0.2f * e0;
            e1 = (e1 > 0.f) ? e1 : 0.2f * e1;
            float w0 = a0 * __expf(e0);
            float w1 = a1 * __expf(e1);
            dsum += w0 + w1;
            *(uint32_t*)&Wt[v * LDH + ub + 2 * j] = packh2(w0, w1);
        }
        dsum += __shfl_xor(dsum, 1, 64);
        dsum += __shfl_xor(dsum, 2, 64);
        if ((tid & 3) == 0) den_l[v] = dsum;
    }
    __syncthreads();
    {
        int vt = w;
        f16x8 af[4];
#pragma unroll
        for (int kt = 0; kt < 4; ++kt) {
            uint4 au = *(const uint4*)&Wt[(vt * 16 + col) * LDH + kt * 32 + kg * 8];
            af[kt] = __builtin_bit_cast(f16x8, au);
        }
        float dn[4];
#pragma unroll
        for (int r = 0; r < 4; ++r) dn[r] = den_l[vt * 16 + kg * 4 + r] + 1e-16f;
#pragma unroll
        for (int ft = 0; ft < 4; ++ft) {
            int f = ft * 16 + col;
            f32x4 acc = {0.f, 0.f, 0.f, 0.f};
#pragma unroll
            for (int kt = 0; kt < 4; ++kt) {
                uint4 bu = *(const uint4*)&Ht[f * LDH + kt * 32 + kg * 8];
                f16x8 bfr = __builtin_bit_cast(f16x8, bu);
                acc = __builtin_amdgcn_mfma_f32_16x16x32_f16(af[kt], bfr, acc, 0, 0, 0);
            }
            float bv = bias[f];
            float ps = 0.f;
#pragma unroll
            for (int r = 0; r < 4; ++r) ps += fmaxf(acc[r] / dn[r] + bv, 0.f);
            ps += __shfl_xor(ps, 16, 64);
            ps += __shfl_xor(ps, 32, 64);
            if (kg == 0) psum[w][f] = ps;
        }
    }
    __syncthreads();
    if (tid < 64) {
        float s = 0.f;
#pragma unroll
        for (int q = 0; q < 8; ++q) s += psum[q][tid];
        emb[tid] = s;
    }
    __syncthreads();
    int rrow = (g & 31) * 4 + (g >> 5);
    for (int dir = 0; dir < 2; ++dir) {
        const float* W = dir ? Wih_b : Wih_f;
        const float* bi = dir ? bib : bif;
        const float* bh = dir ? bhb : bhf;
        for (int o = tid; o < 1024; o += 512) {
            const float* wr = W + (size_t)o * 64;
            float s = bi[o] + bh[o];
#pragma unroll
            for (int k = 0; k < 64; k += 4) {
                float4 wv = *(const float4*)(wr + k);
                s += emb[k] * wv.x + emb[k + 1] * wv.y + emb[k + 2] * wv.z + emb[k + 3] * wv.w;
            }
            xp[dir * 131072 + rrow * 1024 + o] = s;
        }
    }
}

// ---------------- pre-pack Whh to f16 pairs (v7 layout; runs after bufA is dead) ----------
__global__ __launch_bounds__(256) void wpack_kernel(const float* __restrict__ Whh_f,
                                                    const float* __restrict__ Whh_b,
                                                    uint32_t* __restrict__ wreg,
                                                    uint32_t* __restrict__ wtail) {
    int gid = blockIdx.x * 256 + threadIdx.x;   // 0..2047
    int dir = gid >> 10, row = gid & 1023;
    const float* src = (dir ? Whh_b : Whh_f) + (size_t)row * 256;
    uint4* wr4 = (uint4*)wreg;
#pragma unroll
    for (int i = 0; i < 24; ++i) {
        uint4 v;
        v.x = packh2(src[i * 8 + 0], src[i * 8 + 1]);
        v.y = packh2(src[i * 8 + 2], src[i * 8 + 3]);
        v.z = packh2(src[i * 8 + 4], src[i * 8 + 5]);
        v.w = packh2(src[i * 8 + 6], src[i * 8 + 7]);
        wr4[(size_t)(dir * 24 + i) * 1024 + row] = v;
    }
    uint4* wt4 = (uint4*)wtail;
#pragma unroll
    for (int ku = 0; ku < 8; ++ku) {
        const float* s8 = src + 192 + ku * 8;
        uint4 v;
        v.x = packh2(s8[0], s8[1]);
        v.y = packh2(s8[2], s8[3]);
        v.z = packh2(s8[4], s8[5]);
        v.w = packh2(s8[6], s8[7]);
        wt4[(size_t)(dir * 8 + ku) * 1024 + row] = v;
    }
}

// ---------------- BiLSTM recurrent v7 (structural floor ~80us: 512KB weights/step/CU
// through the LDS pipe at ~85B/cy; kept as-is) ---------------------------------------------
__global__ __launch_bounds__(1024, 1) void lstm_kernel(const float* __restrict__ xp,
                                                       const uint32_t* __restrict__ wreg,
                                                       const uint32_t* __restrict__ wtail,
                                                       float* __restrict__ hT) {
    int blk = blockIdx.x;
    int dir = blk >> 2, batch = blk & 3;
    int t = threadIdx.x;                      // gate row 0..1023
    uint32_t wa[96];
    {
        const uint4* ra = (const uint4*)wreg + (size_t)dir * 24 * 1024;
#pragma unroll
        for (int i = 0; i < 24; ++i) {
            uint4 v = ra[i * 1024 + t];
            wa[i * 4 + 0] = v.x; wa[i * 4 + 1] = v.y; wa[i * 4 + 2] = v.z; wa[i * 4 + 3] = v.w;
        }
    }
    __shared__ __align__(16) uint4 wlds[8 * 1024];   // 128 KB tail, [ku][row]
    __shared__ __align__(16) uint32_t h_pk[128];     // h as 128 half2 pairs
    __shared__ float gv[1024];
    {
        const uint4* tsrc = (const uint4*)wtail + (size_t)dir * 8 * 1024;
        for (int i = t; i < 8 * 1024; i += 1024) wlds[i] = tsrc[i];
    }
    if (t < 128) h_pk[t] = 0;
    __syncthreads();
    float creg = 0.f;
    const float* xpb = xp + dir * 131072 + batch * 1024;
#pragma unroll 1
    for (int step = 0; step < 32; ++step) {
        int teff = dir ? (31 - step) : step;
        float xa = xpb[teff * 4096 + t];
        float acc = 0.f;
#pragma unroll
        for (int q = 0; q < 24; ++q) {
            uint4 hq = *(const uint4*)&h_pk[q * 4];   // same-address broadcast b128
            acc = dot2(wa[q * 4 + 0], hq.x, acc);
            acc = dot2(wa[q * 4 + 1], hq.y, acc);
            acc = dot2(wa[q * 4 + 2], hq.z, acc);
            acc = dot2(wa[q * 4 + 3], hq.w, acc);
        }
#pragma unroll
        for (int ku = 0; ku < 8; ++ku) {
            uint4 hq = *(const uint4*)&h_pk[96 + ku * 4];  // broadcast b128
            uint4 qa = wlds[ku * 1024 + t];                // conflict-free b128
            acc = dot2(qa.x, hq.x, acc); acc = dot2(qa.y, hq.y, acc);
            acc = dot2(qa.z, hq.z, acc); acc = dot2(qa.w, hq.w, acc);
        }
        gv[t] = acc + xa;
        __syncthreads();
        if (t < 256) {
            float iv = gv[t], fv = gv[t + 256], gg = gv[t + 512], ov = gv[t + 768];
            creg = sigf(fv) * creg + sigf(iv) * tanhfast(gg);
            float hv = sigf(ov) * tanhfast(creg);
            if (step == 31) hT[(size_t)(dir * 4 + batch) * 256 + t] = hv;
            float hnext = __shfl_down(hv, 1, 64);
            if ((t & 1) == 0) h_pk[t >> 1] = packh2(hv, hnext);
        }
        __syncthreads();
    }
}

// ---------------- heads v2: 129 blocks, 8 threads per output, shfl k-reduce ---------------
__global__ __launch_bounds__(256) void heads_kernel(const float* __restrict__ hT,
                                                    const float* __restrict__ Wmu, const float* __restrict__ bmu,
                                                    const float* __restrict__ Wlv, const float* __restrict__ blv,
                                                    const float* __restrict__ Wpi, const float* __restrict__ bpi,
                                                    float* __restrict__ out) {
    __shared__ __align__(16) float feat[4][512];
    int tid = threadIdx.x;
    for (int i = tid; i < 2048; i += 256) {
        int b = i >> 9, j = i & 511;
        int d = j >> 8, jj = j & 255;
        feat[b][j] = hT[(size_t)(d * 4 + b) * 256 + jj];
    }
    __syncthreads();
    int o = blockIdx.x * 32 + (tid >> 3);     // 32 outputs/block x 8 threads each
    int kp = tid & 7;
    if (o >= 4128) return;
    const float* Wr;
    float bv;
    int kind, m;
    if (o < 2048) { Wr = Wmu + (size_t)o * 512; bv = bmu[o]; kind = 0; m = o; }
    else if (o < 4096) { m = o - 2048; Wr = Wlv + (size_t)m * 512; bv = blv[m]; kind = 1; }
    else { m = o - 4096; Wr = Wpi + (size_t)m * 512; bv = bpi[m]; kind = 2; }
    float s0 = 0.f, s1 = 0.f, s2 = 0.f, s3 = 0.f;
    int k0 = kp * 64;
#pragma unroll
    for (int j = 0; j < 16; ++j) {
        int k = k0 + j * 4;
        float4 wv = *(const float4*)(Wr + k);
        s0 += feat[0][k] * wv.x + feat[0][k + 1] * wv.y + feat[0][k + 2] * wv.z + feat[0][k + 3] * wv.w;
        s1 += feat[1][k] * wv.x + feat[1][k + 1] * wv.y + feat[1][k + 2] * wv.z + feat[1][k + 3] * wv.w;
        s2 += feat[2][k] * wv.x + feat[2][k + 1] * wv.y + feat[2][k + 2] * wv.z + feat[2][k + 3] * wv.w;
        s3 += feat[3][k] * wv.x + feat[3][k + 1] * wv.y + feat[3][k + 2] * wv.z + feat[3][k + 3] * wv.w;
    }
#pragma unroll
    for (int off = 1; off < 8; off <<= 1) {
        s0 += __shfl_xor(s0, off, 64);
        s1 += __shfl_xor(s1, off, 64);
        s2 += __shfl_xor(s2, off, 64);
        s3 += __shfl_xor(s3, off, 64);
    }
    if (kp != 0) return;
    s0 += bv; s1 += bv; s2 += bv; s3 += bv;
    if (kind == 0) {
        out[0 * 2048 + m] = s0; out[1 * 2048 + m] = s1; out[2 * 2048 + m] = s2; out[3 * 2048 + m] = s3;
    } else if (kind == 1) {
        out[8192 + 0 * 2048 + m] = s0; out[8192 + 1 * 2048 + m] = s1;
        out[8192 + 2 * 2048 + m] = s2; out[8192 + 3 * 2048 + m] = s3;
    } else {
        out[16384 + 0 * 32 + m] = s0; out[16384 + 1 * 32 + m] = s1;
        out[16384 + 2 * 32 + m] = s2; out[16384 + 3 * 32 + m] = s3;
    }
}

extern "C" void kernel_launch(void* const* d_in, const int* in_sizes, int n_in,
                              void* d_out, int out_size, void* d_ws, size_t ws_size,
                              hipStream_t stream) {
    const float* x = (const float*)d_in[0];
    const int* ei = (const int*)d_in[1];
    const float* W1 = (const float*)d_in[2];
    const float* as1 = (const float*)d_in[3];
    const float* ad1 = (const float*)d_in[4];
    const float* b1 = (const float*)d_in[5];
    const float* W2 = (const float*)d_in[6];
    const float* as2 = (const float*)d_in[7];
    const float* ad2 = (const float*)d_in[8];
    const float* b2 = (const float*)d_in[9];
    const float* W3 = (const float*)d_in[10];
    const float* as3 = (const float*)d_in[11];
    const float* ad3 = (const float*)d_in[12];
    const float* b3 = (const float*)d_in[13];
    const float* Wih_f = (const float*)d_in[14];
    const float* Whh_f = (const float*)d_in[15];
    const float* bih_f = (const float*)d_in[16];
    const float* bhh_f = (const float*)d_in[17];
    const float* Wih_b = (const float*)d_in[18];
    const float* Whh_b = (const float*)d_in[19];
    const float* bih_b = (const float*)d_in[20];
    const float* bhh_b = (const float*)d_in[21];
    const float* Wmu = (const float*)d_in[22];
    const float* bmu = (const float*)d_in[23];
    const float* Wlv = (const float*)d_in[24];
    const float* blv = (const float*)d_in[25];
    const float* Wpi = (const float*)d_in[26];
    const float* bpi = (const float*)d_in[27];

    float* ws = (float*)d_ws;
    float* bufA = ws;                        // [0, 4194304) feature buffer
    float* bufB = ws + 4194304;              // [4194304, 8388608)
    float* Adj = ws + 8388608;               // 16384
    float* xp = ws + 8404992;                // 262144
    float* hT = ws + 8667136;                // 2048
    _Float16* W1t = (_Float16*)(ws + 8669184);   // 16384 f16 (8192 f32 slots)
    _Float16* W2t = (_Float16*)(ws + 8677376);   // 65536 f16 (32768)
    _Float16* W3t = (_Float16*)(ws + 8710144);   // 16384 f16 (8192) -> ends 8718336
    uint32_t* wreg = (uint32_t*)ws;          // overlaps bufA (dead after aggp)
    uint32_t* wtail = wreg + 196608;
    float* out = (float*)d_out;

    // prep: adjacency + f16-transposed GAT weights (one dispatch)
    prep_kernel<<<224, 256, 0, stream>>>(ei, Adj, W1, W2, W3, W1t, W2t, W3t);

    // GAT layer 1
    gemm_mfma_kernel<256, 64><<<128, 512, 0, stream>>>(x, W1t, bufA);
    aggm_kernel<256><<<128, 512, 0, stream>>>(bufA, as1, ad1, Adj, b1, bufB);
    // GAT layer 2
    gemm_mfma_kernel<256, 256><<<128, 512, 0, stream>>>(bufB, W2t, bufA);
    aggm_kernel<256><<<128, 512, 0, stream>>>(bufA, as2, ad2, Adj, b2, bufB);
    // GAT layer 3 + pool + xpart (fused)
    gemm_mfma_kernel<64, 256><<<128, 512, 0, stream>>>(bufB, W3t, bufA);
    aggp_kernel<<<128, 512, 0, stream>>>(bufA, as3, ad3, Adj, b3,
                                         Wih_f, bih_f, bhh_f, Wih_b, bih_b, bhh_b, xp);
    // bufA dead -> wreg/wtail may overwrite it
    wpack_kernel<<<8, 256, 0, stream>>>(Whh_f, Whh_b, wreg, wtail);
    lstm_kernel<<<8, 1024, 0, stream>>>(xp, wreg, wtail, hT);
    heads_kernel<<<129, 256, 0, stream>>>(hT, Wmu, bmu, Wlv, blv, Wpi, bpi, out);
}

// Round 15
// 211.885 us; speedup vs baseline: 2.0008x; 1.1701x over previous
//
#include <hip/hip_runtime.h>
#include <hip/hip_bf16.h>
#include <cstdint>

#define NLOC 128        // nodes per graph
#define NGRAPH 128      // bs*T
#define NNODE 16384     // total nodes
#define EBASE 2048      // base edges per graph

typedef _Float16 half2v __attribute__((ext_vector_type(2)));
typedef _Float16 f16x8 __attribute__((ext_vector_type(8)));
typedef float f32x4 __attribute__((ext_vector_type(4)));

__device__ __forceinline__ float sigf(float x) { return 1.f / (1.f + __expf(-x)); }
__device__ __forceinline__ float tanhfast(float x) {
    float e = __expf(2.f * x);
    return 1.f - 2.f / (e + 1.f);
}
__device__ __forceinline__ uint32_t packh2(float a, float b) {
    half2v v;
    v.x = (_Float16)a; v.y = (_Float16)b;
    return __builtin_bit_cast(uint32_t, v);
}
__device__ __forceinline__ float dot2(uint32_t w, uint32_t h, float acc) {
#if __has_builtin(__builtin_amdgcn_fdot2)
    return __builtin_amdgcn_fdot2(__builtin_bit_cast(half2v, w),
                                  __builtin_bit_cast(half2v, h), acc, false);
#else
    half2v wv = __builtin_bit_cast(half2v, w);
    half2v hv = __builtin_bit_cast(half2v, h);
    return acc + (float)wv.x * (float)hv.x + (float)wv.y * (float)hv.y;
#endif
}

// ---------------- prep: adjacency + f16-transposed GAT weights + LSTM wpack ---------------
// blocks 0..127: Adj; 128..143: W1t; 144..207: W2t; 208..223: W3t; 224..231: Whh pack
__global__ __launch_bounds__(256) void prep_kernel(const int* __restrict__ ei,
                                                   float* __restrict__ Adj,
                                                   const float* __restrict__ W1,
                                                   const float* __restrict__ W2,
                                                   const float* __restrict__ W3,
                                                   _Float16* __restrict__ W1t,
                                                   _Float16* __restrict__ W2t,
                                                   _Float16* __restrict__ W3t,
                                                   const float* __restrict__ Whh_f,
                                                   const float* __restrict__ Whh_b,
                                                   uint32_t* __restrict__ wreg,
                                                   uint32_t* __restrict__ wtail) {
    int b = blockIdx.x, tid = threadIdx.x;
    if (b < 128) {
        __shared__ int rowA[NLOC];
        int v = b;
        if (tid < NLOC) rowA[tid] = 0;
        __syncthreads();
        const int* srcs = ei;
        const int* dsts = ei + EBASE;
        int e0 = tid * 8;
#pragma unroll
        for (int k = 0; k < 8; ++k)
            if (dsts[e0 + k] == v) atomicAdd(&rowA[srcs[e0 + k]], 1);
        __syncthreads();
        if (tid < NLOC) Adj[v * NLOC + tid] = (float)rowA[tid] + (tid == v ? 1.f : 0.f);
    } else if (b < 144) {
        int i = (b - 128) * 1024 + tid * 4;
        int n = i >> 6, k = i & 63;
#pragma unroll
        for (int j = 0; j < 4; ++j) W1t[n * 64 + k + j] = (_Float16)W1[(size_t)(k + j) * 256 + n];
    } else if (b < 208) {
        int i = (b - 144) * 1024 + tid * 4;
        int n = i >> 8, k = i & 255;
#pragma unroll
        for (int j = 0; j < 4; ++j) W2t[n * 256 + k + j] = (_Float16)W2[(size_t)(k + j) * 256 + n];
    } else if (b < 224) {
        int i = (b - 208) * 1024 + tid * 4;
        int n = i >> 8, k = i & 255;
#pragma unroll
        for (int j = 0; j < 4; ++j) W3t[n * 256 + k + j] = (_Float16)W3[(size_t)(k + j) * 64 + n];
    } else {
        int gid = (b - 224) * 256 + tid;       // 0..2047
        int dir = gid >> 10, row = gid & 1023;
        const float* src = (dir ? Whh_b : Whh_f) + (size_t)row * 256;
        uint4* wr4 = (uint4*)wreg;
#pragma unroll
        for (int i = 0; i < 24; ++i) {
            uint4 v;
            v.x = packh2(src[i * 8 + 0], src[i * 8 + 1]);
            v.y = packh2(src[i * 8 + 2], src[i * 8 + 3]);
            v.z = packh2(src[i * 8 + 4], src[i * 8 + 5]);
            v.w = packh2(src[i * 8 + 6], src[i * 8 + 7]);
            wr4[(size_t)(dir * 24 + i) * 1024 + row] = v;
        }
        uint4* wt4 = (uint4*)wtail;
#pragma unroll
        for (int ku = 0; ku < 8; ++ku) {
            const float* s8 = src + 192 + ku * 8;
            uint4 v;
            v.x = packh2(s8[0], s8[1]);
            v.y = packh2(s8[2], s8[3]);
            v.z = packh2(s8[4], s8[5]);
            v.w = packh2(s8[6], s8[7]);
            wt4[(size_t)(dir * 8 + ku) * 1024 + row] = v;
        }
    }
}

// ---------------- fused GAT layer: GEMM(MFMA) + attention dots + aggregation(MFMA) --------
// One block per graph, 512 thr, 8 waves (2m x 4n). H = A@W computed in f32 accumulators;
// attention dots taken from the accumulators (16-lane shfl tree, deterministic) and H
// packed to f16 Ht in LDS — H never hits global. Then the R13-verified aggregation MFMA.
// LDS aliasing: As,Bs (GEMM) die before Ht,Wt (agg) are written; regions overlap.
// POOLX (layer 3): fuses graph-pool + LSTM input matvec; out = xp.
template <int K, int N, bool POOLX>
__global__ __launch_bounds__(512) void fl_kernel(const float* __restrict__ A,
                                                 const _Float16* __restrict__ Wg,
                                                 const float* __restrict__ a_s,
                                                 const float* __restrict__ a_d,
                                                 const float* __restrict__ Adj,
                                                 const float* __restrict__ bias,
                                                 const float* __restrict__ Wih_f, const float* __restrict__ bif, const float* __restrict__ bhf,
                                                 const float* __restrict__ Wih_b, const float* __restrict__ bib, const float* __restrict__ bhb,
                                                 float* __restrict__ outG) {
    constexpr int H = N / 64;
    constexpr int NT = N / 64;                    // n-tiles per wave (16 cols each)
    constexpr int LDA = K + 4;
    constexpr int LDB = 68;
    constexpr int LDH = 136;
    constexpr int ASB = 128 * LDA * 2;
    constexpr int HTB = N * LDH * 2;
    constexpr int R1 = (ASB > HTB) ? ASB : HTB;
    constexpr int R2 = 128 * LDH * 2;             // Wt (>= Bs = N*LDB*2)
    __shared__ __align__(16) char raw[R1 + R2];
    _Float16* As = (_Float16*)raw;
    _Float16* Ht = (_Float16*)raw;                // aliases As (As dead first)
    _Float16* Bs = (_Float16*)(raw + R1);
    _Float16* Wt = (_Float16*)(raw + R1);         // aliases Bs
    __shared__ float as_l[128 * H];
    __shared__ float ad_l[128 * H];
    __shared__ float den_l[128];
    __shared__ float as_part[4][128];
    __shared__ float ad_part[4][128];
    __shared__ float psum[8][64];
    __shared__ float emb[64];

    int g = blockIdx.x, tid = threadIdx.x;
    int lane = tid & 63, w = tid >> 6;
    int wm = w >> 2, wn = w & 3;
    int col = lane & 15, kg = lane >> 4;
    size_t base = (size_t)g * 128;

    // attention coefficient lookups for this lane's f-columns
    float asc[NT], adc[NT];
#pragma unroll
    for (int nt = 0; nt < NT; ++nt) {
        int f = (wn * NT + nt) * 16 + col;
        asc[nt] = a_s[f];
        adc[nt] = a_d[f];
    }
    // ---- stage A (f32 -> f16)
    {
        const float* src = A + base * K;
        for (int i = tid; i < 128 * K / 2; i += 512) {
            int m = (2 * i) / K, k = (2 * i) % K;
            float2 v = *(const float2*)(src + (size_t)m * K + k);
            *(uint32_t*)&As[m * LDA + k] = packh2(v.x, v.y);
        }
    }
    // ---- GEMM: acc[mt 0..3][nt] covers this wave's 64 m-rows x 64*NT/4... (16*NT cols)
    f32x4 acc[4][NT];
#pragma unroll
    for (int mt = 0; mt < 4; ++mt)
#pragma unroll
        for (int nt = 0; nt < NT; ++nt) acc[mt][nt] = (f32x4){0.f, 0.f, 0.f, 0.f};
#pragma unroll 1
    for (int kc = 0; kc < K / 64; ++kc) {
        __syncthreads();
        for (int j = tid; j < N * 8; j += 512) {
            int n = j >> 3, ko = (j & 7) * 8;
            *(uint4*)&Bs[n * LDB + ko] = *(const uint4*)&Wg[(size_t)n * K + kc * 64 + ko];
        }
        __syncthreads();
        uint4 bf[NT][2];
#pragma unroll
        for (int nt = 0; nt < NT; ++nt) {
            int nb = (wn * NT + nt) * 16 + col;
            bf[nt][0] = *(const uint4*)&Bs[nb * LDB + kg * 8];
            bf[nt][1] = *(const uint4*)&Bs[nb * LDB + 32 + kg * 8];
        }
#pragma unroll
        for (int mt = 0; mt < 4; ++mt) {
            int mrow = wm * 64 + mt * 16 + col;
            uint4 a0 = *(const uint4*)&As[mrow * LDA + kc * 64 + kg * 8];
            uint4 a1 = *(const uint4*)&As[mrow * LDA + kc * 64 + 32 + kg * 8];
#pragma unroll
            for (int nt = 0; nt < NT; ++nt) {
                acc[mt][nt] = __builtin_amdgcn_mfma_f32_16x16x32_f16(
                    __builtin_bit_cast(f16x8, a0), __builtin_bit_cast(f16x8, bf[nt][0]),
                    acc[mt][nt], 0, 0, 0);
                acc[mt][nt] = __builtin_amdgcn_mfma_f32_16x16x32_f16(
                    __builtin_bit_cast(f16x8, a1), __builtin_bit_cast(f16x8, bf[nt][1]),
                    acc[mt][nt], 0, 0, 0);
            }
        }
    }
    __syncthreads();    // all As/Bs reads done -> Ht/Wt may overwrite
    // ---- phase 2: Ht (f16 transposed) + attention dots from f32 accumulators
#pragma unroll
    for (int mt = 0; mt < 4; ++mt) {
        int mb = wm * 64 + mt * 16;
        float pas[4] = {0.f, 0.f, 0.f, 0.f}, pdd[4] = {0.f, 0.f, 0.f, 0.f};
#pragma unroll
        for (int nt = 0; nt < NT; ++nt) {
#pragma unroll
            for (int r = 0; r < 4; ++r) {
                float hv = acc[mt][nt][r];
                pas[r] += hv * asc[nt];
                pdd[r] += hv * adc[nt];
            }
            int f = (wn * NT + nt) * 16 + col;
            *(uint32_t*)&Ht[f * LDH + mb + kg * 4] = packh2(acc[mt][nt][0], acc[mt][nt][1]);
            *(uint32_t*)&Ht[f * LDH + mb + kg * 4 + 2] = packh2(acc[mt][nt][2], acc[mt][nt][3]);
        }
#pragma unroll
        for (int off = 1; off < 16; off <<= 1)
#pragma unroll
            for (int r = 0; r < 4; ++r) {
                pas[r] += __shfl_xor(pas[r], off, 64);
                pdd[r] += __shfl_xor(pdd[r], off, 64);
            }
        if (col == 0) {
#pragma unroll
            for (int r = 0; r < 4; ++r) {
                int m = mb + kg * 4 + r;
                if constexpr (N == 256) {
                    as_l[m * 4 + wn] = pas[r];    // wn == head
                    ad_l[m * 4 + wn] = pdd[r];
                } else {
                    as_part[wn][m] = pas[r];      // 16-f slices of the single head
                    ad_part[wn][m] = pdd[r];
                }
            }
        }
    }
    __syncthreads();
    if constexpr (N == 64) {
        if (tid < 128) {
            as_l[tid] = as_part[0][tid] + as_part[1][tid] + as_part[2][tid] + as_part[3][tid];
            ad_l[tid] = ad_part[0][tid] + ad_part[1][tid] + ad_part[2][tid] + ad_part[3][tid];
        }
        __syncthreads();
    }
    // ---- phase 3: aggregation (R13-verified structure)
    for (int h = 0; h < H; ++h) {
        {
            int v = tid >> 2, ub = (tid & 3) * 32;
            float advv = ad_l[v * H + h];
            const float* arow = Adj + (size_t)v * 128 + ub;
            float dsum = 0.f;
#pragma unroll
            for (int j = 0; j < 16; ++j) {
                float a0 = arow[2 * j], a1 = arow[2 * j + 1];
                float e0 = as_l[(ub + 2 * j) * H + h] + advv;
                float e1 = as_l[(ub + 2 * j + 1) * H + h] + advv;
                e0 = (e0 > 0.f) ? e0 : 0.2f * e0;
                e1 = (e1 > 0.f) ? e1 : 0.2f * e1;
                float w0 = a0 * __expf(e0);
                float w1 = a1 * __expf(e1);
                dsum += w0 + w1;
                *(uint32_t*)&Wt[v * LDH + ub + 2 * j] = packh2(w0, w1);
            }
            dsum += __shfl_xor(dsum, 1, 64);
            dsum += __shfl_xor(dsum, 2, 64);
            if ((tid & 3) == 0) den_l[v] = dsum;
        }
        __syncthreads();
        {
            int vt = w;
            f16x8 af[4];
#pragma unroll
            for (int kt = 0; kt < 4; ++kt) {
                uint4 au = *(const uint4*)&Wt[(vt * 16 + col) * LDH + kt * 32 + kg * 8];
                af[kt] = __builtin_bit_cast(f16x8, au);
            }
            float dn[4];
#pragma unroll
            for (int r = 0; r < 4; ++r) dn[r] = den_l[vt * 16 + kg * 4 + r] + 1e-16f;
#pragma unroll
            for (int ft = 0; ft < 4; ++ft) {
                int f = h * 64 + ft * 16 + col;
                f32x4 oacc = {0.f, 0.f, 0.f, 0.f};
#pragma unroll
                for (int kt = 0; kt < 4; ++kt) {
                    uint4 bu = *(const uint4*)&Ht[f * LDH + kt * 32 + kg * 8];
                    oacc = __builtin_amdgcn_mfma_f32_16x16x32_f16(
                        af[kt], __builtin_bit_cast(f16x8, bu), oacc, 0, 0, 0);
                }
                float bv = bias[f];
                if constexpr (!POOLX) {
#pragma unroll
                    for (int r = 0; r < 4; ++r) {
                        int v = vt * 16 + kg * 4 + r;
                        float o = oacc[r] / dn[r] + bv;
                        outG[(size_t)(base + v) * N + f] = fmaxf(o, 0.f);
                    }
                } else {
                    float ps = 0.f;
#pragma unroll
                    for (int r = 0; r < 4; ++r) ps += fmaxf(oacc[r] / dn[r] + bv, 0.f);
                    ps += __shfl_xor(ps, 16, 64);
                    ps += __shfl_xor(ps, 32, 64);
                    if (kg == 0) psum[w][f] = ps;
                }
            }
        }
        __syncthreads();
    }
    if constexpr (POOLX) {
        if (tid < 64) {
            float s = 0.f;
#pragma unroll
            for (int q = 0; q < 8; ++q) s += psum[q][tid];
            emb[tid] = s;
        }
        __syncthreads();
        int rrow = (g & 31) * 4 + (g >> 5);
        for (int dir = 0; dir < 2; ++dir) {
            const float* W = dir ? Wih_b : Wih_f;
            const float* bi = dir ? bib : bif;
            const float* bh = dir ? bhb : bhf;
            for (int o = tid; o < 1024; o += 512) {
                const float* wr = W + (size_t)o * 64;
                float s = bi[o] + bh[o];
#pragma unroll
                for (int k = 0; k < 64; k += 4) {
                    float4 wv = *(const float4*)(wr + k);
                    s += emb[k] * wv.x + emb[k + 1] * wv.y + emb[k + 2] * wv.z + emb[k + 3] * wv.w;
                }
                outG[dir * 131072 + rrow * 1024 + o] = s;
            }
        }
    }
}

// ---------------- BiLSTM recurrent v7 (L2 weight-stream floor ~75us on 8 CUs; control) ----
__global__ __launch_bounds__(1024, 1) void lstm_kernel(const float* __restrict__ xp,
                                                       const uint32_t* __restrict__ wreg,
                                                       const uint32_t* __restrict__ wtail,
                                                       float* __restrict__ hT) {
    int blk = blockIdx.x;
    int dir = blk >> 2, batch = blk & 3;
    int t = threadIdx.x;                      // gate row 0..1023
    uint32_t wa[96];
    {
        const uint4* ra = (const uint4*)wreg + (size_t)dir * 24 * 1024;
#pragma unroll
        for (int i = 0; i < 24; ++i) {
            uint4 v = ra[i * 1024 + t];
            wa[i * 4 + 0] = v.x; wa[i * 4 + 1] = v.y; wa[i * 4 + 2] = v.z; wa[i * 4 + 3] = v.w;
        }
    }
    __shared__ __align__(16) uint4 wlds[8 * 1024];   // 128 KB tail, [ku][row]
    __shared__ __align__(16) uint32_t h_pk[128];     // h as 128 half2 pairs
    __shared__ float gv[1024];
    {
        const uint4* tsrc = (const uint4*)wtail + (size_t)dir * 8 * 1024;
        for (int i = t; i < 8 * 1024; i += 1024) wlds[i] = tsrc[i];
    }
    if (t < 128) h_pk[t] = 0;
    __syncthreads();
    float creg = 0.f;
    const float* xpb = xp + dir * 131072 + batch * 1024;
#pragma unroll 1
    for (int step = 0; step < 32; ++step) {
        int teff = dir ? (31 - step) : step;
        float xa = xpb[teff * 4096 + t];
        float acc = 0.f;
#pragma unroll
        for (int q = 0; q < 24; ++q) {
            uint4 hq = *(const uint4*)&h_pk[q * 4];   // same-address broadcast b128
            acc = dot2(wa[q * 4 + 0], hq.x, acc);
            acc = dot2(wa[q * 4 + 1], hq.y, acc);
            acc = dot2(wa[q * 4 + 2], hq.z, acc);
            acc = dot2(wa[q * 4 + 3], hq.w, acc);
        }
#pragma unroll
        for (int ku = 0; ku < 8; ++ku) {
            uint4 hq = *(const uint4*)&h_pk[96 + ku * 4];  // broadcast b128
            uint4 qa = wlds[ku * 1024 + t];                // conflict-free b128
            acc = dot2(qa.x, hq.x, acc); acc = dot2(qa.y, hq.y, acc);
            acc = dot2(qa.z, hq.z, acc); acc = dot2(qa.w, hq.w, acc);
        }
        gv[t] = acc + xa;
        __syncthreads();
        if (t < 256) {
            float iv = gv[t], fv = gv[t + 256], gg = gv[t + 512], ov = gv[t + 768];
            creg = sigf(fv) * creg + sigf(iv) * tanhfast(gg);
            float hv = sigf(ov) * tanhfast(creg);
            if (step == 31) hT[(size_t)(dir * 4 + batch) * 256 + t] = hv;
            float hnext = __shfl_down(hv, 1, 64);
            if ((t & 1) == 0) h_pk[t >> 1] = packh2(hv, hnext);
        }
        __syncthreads();
    }
}

// ---------------- heads v2: 129 blocks, 8 threads per output, shfl k-reduce ---------------
__global__ __launch_bounds__(256) void heads_kernel(const float* __restrict__ hT,
                                                    const float* __restrict__ Wmu, const float* __restrict__ bmu,
                                                    const float* __restrict__ Wlv, const float* __restrict__ blv,
                                                    const float* __restrict__ Wpi, const float* __restrict__ bpi,
                                                    float* __restrict__ out) {
    __shared__ __align__(16) float feat[4][512];
    int tid = threadIdx.x;
    for (int i = tid; i < 2048; i += 256) {
        int b = i >> 9, j = i & 511;
        int d = j >> 8, jj = j & 255;
        feat[b][j] = hT[(size_t)(d * 4 + b) * 256 + jj];
    }
    __syncthreads();
    int o = blockIdx.x * 32 + (tid >> 3);     // 32 outputs/block x 8 threads each
    int kp = tid & 7;
    if (o >= 4128) return;
    const float* Wr;
    float bv;
    int kind, m;
    if (o < 2048) { Wr = Wmu + (size_t)o * 512; bv = bmu[o]; kind = 0; m = o; }
    else if (o < 4096) { m = o - 2048; Wr = Wlv + (size_t)m * 512; bv = blv[m]; kind = 1; }
    else { m = o - 4096; Wr = Wpi + (size_t)m * 512; bv = bpi[m]; kind = 2; }
    float s0 = 0.f, s1 = 0.f, s2 = 0.f, s3 = 0.f;
    int k0 = kp * 64;
#pragma unroll
    for (int j = 0; j < 16; ++j) {
        int k = k0 + j * 4;
        float4 wv = *(const float4*)(Wr + k);
        s0 += feat[0][k] * wv.x + feat[0][k + 1] * wv.y + feat[0][k + 2] * wv.z + feat[0][k + 3] * wv.w;
        s1 += feat[1][k] * wv.x + feat[1][k + 1] * wv.y + feat[1][k + 2] * wv.z + feat[1][k + 3] * wv.w;
        s2 += feat[2][k] * wv.x + feat[2][k + 1] * wv.y + feat[2][k + 2] * wv.z + feat[2][k + 3] * wv.w;
        s3 += feat[3][k] * wv.x + feat[3][k + 1] * wv.y + feat[3][k + 2] * wv.z + feat[3][k + 3] * wv.w;
    }
#pragma unroll
    for (int off = 1; off < 8; off <<= 1) {
        s0 += __shfl_xor(s0, off, 64);
        s1 += __shfl_xor(s1, off, 64);
        s2 += __shfl_xor(s2, off, 64);
        s3 += __shfl_xor(s3, off, 64);
    }
    if (kp != 0) return;
    s0 += bv; s1 += bv; s2 += bv; s3 += bv;
    if (kind == 0) {
        out[0 * 2048 + m] = s0; out[1 * 2048 + m] = s1; out[2 * 2048 + m] = s2; out[3 * 2048 + m] = s3;
    } else if (kind == 1) {
        out[8192 + 0 * 2048 + m] = s0; out[8192 + 1 * 2048 + m] = s1;
        out[8192 + 2 * 2048 + m] = s2; out[8192 + 3 * 2048 + m] = s3;
    } else {
        out[16384 + 0 * 32 + m] = s0; out[16384 + 1 * 32 + m] = s1;
        out[16384 + 2 * 32 + m] = s2; out[16384 + 3 * 32 + m] = s3;
    }
}

extern "C" void kernel_launch(void* const* d_in, const int* in_sizes, int n_in,
                              void* d_out, int out_size, void* d_ws, size_t ws_size,
                              hipStream_t stream) {
    const float* x = (const float*)d_in[0];
    const int* ei = (const int*)d_in[1];
    const float* W1 = (const float*)d_in[2];
    const float* as1 = (const float*)d_in[3];
    const float* ad1 = (const float*)d_in[4];
    const float* b1 = (const float*)d_in[5];
    const float* W2 = (const float*)d_in[6];
    const float* as2 = (const float*)d_in[7];
    const float* ad2 = (const float*)d_in[8];
    const float* b2 = (const float*)d_in[9];
    const float* W3 = (const float*)d_in[10];
    const float* as3 = (const float*)d_in[11];
    const float* ad3 = (const float*)d_in[12];
    const float* b3 = (const float*)d_in[13];
    const float* Wih_f = (const float*)d_in[14];
    const float* Whh_f = (const float*)d_in[15];
    const float* bih_f = (const float*)d_in[16];
    const float* bhh_f = (const float*)d_in[17];
    const float* Wih_b = (const float*)d_in[18];
    const float* Whh_b = (const float*)d_in[19];
    const float* bih_b = (const float*)d_in[20];
    const float* bhh_b = (const float*)d_in[21];
    const float* Wmu = (const float*)d_in[22];
    const float* bmu = (const float*)d_in[23];
    const float* Wlv = (const float*)d_in[24];
    const float* blv = (const float*)d_in[25];
    const float* Wpi = (const float*)d_in[26];
    const float* bpi = (const float*)d_in[27];

    float* ws = (float*)d_ws;
    float* buf1 = ws;                        // [0, 4194304)
    float* buf2 = ws + 4194304;              // [4194304, 8388608)
    float* Adj = ws + 8388608;               // 16384
    float* xp = ws + 8404992;                // 262144
    float* hT = ws + 8667136;                // 2048
    _Float16* W1t = (_Float16*)(ws + 8669184);   // 16384 f16
    _Float16* W2t = (_Float16*)(ws + 8677376);   // 65536 f16
    _Float16* W3t = (_Float16*)(ws + 8710144);   // 16384 f16 -> ends 8718336
    uint32_t* wreg = (uint32_t*)(ws + 8718336);  // 196608 u32 (dedicated, no overlap)
    uint32_t* wtail = wreg + 196608;             // 65536 u32 -> ends 8980480 f32 (~35.9MB)
    float* out = (float*)d_out;

    // prep: adjacency + f16 GAT weights + LSTM weight pack (one dispatch)
    prep_kernel<<<232, 256, 0, stream>>>(ei, Adj, W1, W2, W3, W1t, W2t, W3t,
                                         Whh_f, Whh_b, wreg, wtail);
    // GAT layers (fully fused per layer)
    fl_kernel<64, 256, false><<<128, 512, 0, stream>>>(x, W1t, as1, ad1, Adj, b1,
        Wih_f, bih_f, bhh_f, Wih_b, bih_b, bhh_b, buf1);
    fl_kernel<256, 256, false><<<128, 512, 0, stream>>>(buf1, W2t, as2, ad2, Adj, b2,
        Wih_f, bih_f, bhh_f, Wih_b, bih_b, bhh_b, buf2);
    fl_kernel<256, 64, true><<<128, 512, 0, stream>>>(buf2, W3t, as3, ad3, Adj, b3,
        Wih_f, bih_f, bhh_f, Wih_b, bih_b, bhh_b, xp);
    // recurrent + heads
    lstm_kernel<<<8, 1024, 0, stream>>>(xp, wreg, wtail, hT);
    heads_kernel<<<129, 256, 0, stream>>>(hT, Wmu, bmu, Wlv, blv, Wpi, bpi, out);
}

// Round 16
// 193.517 us; speedup vs baseline: 2.1907x; 1.0949x over previous
//
#include <hip/hip_runtime.h>
#include <hip/hip_bf16.h>
#include <cstdint>

#define NLOC 128        // nodes per graph
#define NGRAPH 128      // bs*T
#define NNODE 16384     // total nodes
#define EBASE 2048      // base edges per graph

typedef _Float16 half2v __attribute__((ext_vector_type(2)));
typedef _Float16 f16x8 __attribute__((ext_vector_type(8)));
typedef float f32x4 __attribute__((ext_vector_type(4)));

__device__ __forceinline__ float sigf(float x) { return 1.f / (1.f + __expf(-x)); }
__device__ __forceinline__ float tanhfast(float x) {
    float e = __expf(2.f * x);
    return 1.f - 2.f / (e + 1.f);
}
__device__ __forceinline__ uint32_t packh2(float a, float b) {
    half2v v;
    v.x = (_Float16)a; v.y = (_Float16)b;
    return __builtin_bit_cast(uint32_t, v);
}
__device__ __forceinline__ float dot2(uint32_t w, uint32_t h, float acc) {
#if __has_builtin(__builtin_amdgcn_fdot2)
    return __builtin_amdgcn_fdot2(__builtin_bit_cast(half2v, w),
                                  __builtin_bit_cast(half2v, h), acc, false);
#else
    half2v wv = __builtin_bit_cast(half2v, w);
    half2v hv = __builtin_bit_cast(half2v, h);
    return acc + (float)wv.x * (float)hv.x + (float)wv.y * (float)hv.y;
#endif
}

// ---------------- prep: adjacency + f16-transposed GAT weights + LSTM wpack ---------------
__global__ __launch_bounds__(256) void prep_kernel(const int* __restrict__ ei,
                                                   float* __restrict__ Adj,
                                                   const float* __restrict__ W1,
                                                   const float* __restrict__ W2,
                                                   const float* __restrict__ W3,
                                                   _Float16* __restrict__ W1t,
                                                   _Float16* __restrict__ W2t,
                                                   _Float16* __restrict__ W3t,
                                                   const float* __restrict__ Whh_f,
                                                   const float* __restrict__ Whh_b,
                                                   uint32_t* __restrict__ wreg,
                                                   uint32_t* __restrict__ wtail) {
    int b = blockIdx.x, tid = threadIdx.x;
    if (b < 128) {
        __shared__ int rowA[NLOC];
        int v = b;
        if (tid < NLOC) rowA[tid] = 0;
        __syncthreads();
        const int* srcs = ei;
        const int* dsts = ei + EBASE;
        int e0 = tid * 8;
#pragma unroll
        for (int k = 0; k < 8; ++k)
            if (dsts[e0 + k] == v) atomicAdd(&rowA[srcs[e0 + k]], 1);
        __syncthreads();
        if (tid < NLOC) Adj[v * NLOC + tid] = (float)rowA[tid] + (tid == v ? 1.f : 0.f);
    } else if (b < 144) {
        int i = (b - 128) * 1024 + tid * 4;
        int n = i >> 6, k = i & 63;
#pragma unroll
        for (int j = 0; j < 4; ++j) W1t[n * 64 + k + j] = (_Float16)W1[(size_t)(k + j) * 256 + n];
    } else if (b < 208) {
        int i = (b - 144) * 1024 + tid * 4;
        int n = i >> 8, k = i & 255;
#pragma unroll
        for (int j = 0; j < 4; ++j) W2t[n * 256 + k + j] = (_Float16)W2[(size_t)(k + j) * 256 + n];
    } else if (b < 224) {
        int i = (b - 208) * 1024 + tid * 4;
        int n = i >> 8, k = i & 255;
#pragma unroll
        for (int j = 0; j < 4; ++j) W3t[n * 256 + k + j] = (_Float16)W3[(size_t)(k + j) * 64 + n];
    } else {
        int gid = (b - 224) * 256 + tid;       // 0..2047
        int dir = gid >> 10, row = gid & 1023;
        const float* src = (dir ? Whh_b : Whh_f) + (size_t)row * 256;
        uint4* wr4 = (uint4*)wreg;
#pragma unroll
        for (int i = 0; i < 24; ++i) {
            uint4 v;
            v.x = packh2(src[i * 8 + 0], src[i * 8 + 1]);
            v.y = packh2(src[i * 8 + 2], src[i * 8 + 3]);
            v.z = packh2(src[i * 8 + 4], src[i * 8 + 5]);
            v.w = packh2(src[i * 8 + 6], src[i * 8 + 7]);
            wr4[(size_t)(dir * 24 + i) * 1024 + row] = v;
        }
        uint4* wt4 = (uint4*)wtail;
#pragma unroll
        for (int ku = 0; ku < 8; ++ku) {
            const float* s8 = src + 192 + ku * 8;
            uint4 v;
            v.x = packh2(s8[0], s8[1]);
            v.y = packh2(s8[2], s8[3]);
            v.z = packh2(s8[4], s8[5]);
            v.w = packh2(s8[6], s8[7]);
            wt4[(size_t)(dir * 8 + ku) * 1024 + row] = v;
        }
    }
}

// ---------------- fused GAT layer, head-split: grid (128 graphs x NF/NL) ------------------
// Each block computes NL features (NL/64 heads) of one graph: half-GEMM + its heads'
// attention dots + aggregation. A staged per block (dup, cheap); H never hits global.
// NT = n-tiles/wave = NL/64; HL = local heads = NL/64; WPH = waves per head = 4/HL.
// Dots always via as_part partial-combine (verified N=64 path, R14/R15).
template <int K, int NL, int NF, bool POOLX>
__global__ __launch_bounds__(512) void fl_kernel(const float* __restrict__ A,
                                                 const _Float16* __restrict__ Wg,
                                                 const float* __restrict__ a_s,
                                                 const float* __restrict__ a_d,
                                                 const float* __restrict__ Adj,
                                                 const float* __restrict__ bias,
                                                 const float* __restrict__ Wih_f, const float* __restrict__ bif, const float* __restrict__ bhf,
                                                 const float* __restrict__ Wih_b, const float* __restrict__ bib, const float* __restrict__ bhb,
                                                 float* __restrict__ outG) {
    constexpr int HL = NL / 64;
    constexpr int NT = NL / 64;
    constexpr int WPH = 4 / HL;
    constexpr int LDA = K + 4;
    constexpr int LDB = 68;
    constexpr int LDH = 136;
    constexpr int ASB = 128 * LDA * 2;
    constexpr int HTB = NL * LDH * 2;
    constexpr int R1 = (ASB > HTB) ? ASB : HTB;
    constexpr int R2 = 128 * LDH * 2;             // Wt (>= Bs = NL*LDB*2)
    __shared__ __align__(16) char raw[R1 + R2];
    _Float16* As = (_Float16*)raw;
    _Float16* Ht = (_Float16*)raw;                // aliases As (As dead first)
    _Float16* Bs = (_Float16*)(raw + R1);
    _Float16* Wt = (_Float16*)(raw + R1);         // aliases Bs
    __shared__ float as_l[128 * HL];
    __shared__ float ad_l[128 * HL];
    __shared__ float den_l[128];
    __shared__ float as_part[4][128];
    __shared__ float ad_part[4][128];
    __shared__ float psum[8][64];
    __shared__ float emb[64];

    int g = blockIdx.x, tid = threadIdx.x;
    int foff = blockIdx.y * NL;                   // global feature offset of this block
    int lane = tid & 63, w = tid >> 6;
    int wm = w >> 2, wn = w & 3;
    int col = lane & 15, kg = lane >> 4;
    size_t base = (size_t)g * 128;

    float asc[NT], adc[NT];
#pragma unroll
    for (int nt = 0; nt < NT; ++nt) {
        int f = foff + (wn * NT + nt) * 16 + col;
        asc[nt] = a_s[f];
        adc[nt] = a_d[f];
    }
    // ---- stage A (f32 -> f16)
    {
        const float* src = A + base * K;
        for (int i = tid; i < 128 * K / 2; i += 512) {
            int m = (2 * i) / K, k = (2 * i) % K;
            float2 v = *(const float2*)(src + (size_t)m * K + k);
            *(uint32_t*)&As[m * LDA + k] = packh2(v.x, v.y);
        }
    }
    // ---- GEMM
    f32x4 acc[4][NT];
#pragma unroll
    for (int mt = 0; mt < 4; ++mt)
#pragma unroll
        for (int nt = 0; nt < NT; ++nt) acc[mt][nt] = (f32x4){0.f, 0.f, 0.f, 0.f};
#pragma unroll 1
    for (int kc = 0; kc < K / 64; ++kc) {
        __syncthreads();
        for (int j = tid; j < NL * 8; j += 512) {
            int n = j >> 3, ko = (j & 7) * 8;
            *(uint4*)&Bs[n * LDB + ko] = *(const uint4*)&Wg[(size_t)(foff + n) * K + kc * 64 + ko];
        }
        __syncthreads();
        uint4 bf[NT][2];
#pragma unroll
        for (int nt = 0; nt < NT; ++nt) {
            int nb = (wn * NT + nt) * 16 + col;
            bf[nt][0] = *(const uint4*)&Bs[nb * LDB + kg * 8];
            bf[nt][1] = *(const uint4*)&Bs[nb * LDB + 32 + kg * 8];
        }
#pragma unroll
        for (int mt = 0; mt < 4; ++mt) {
            int mrow = wm * 64 + mt * 16 + col;
            uint4 a0 = *(const uint4*)&As[mrow * LDA + kc * 64 + kg * 8];
            uint4 a1 = *(const uint4*)&As[mrow * LDA + kc * 64 + 32 + kg * 8];
#pragma unroll
            for (int nt = 0; nt < NT; ++nt) {
                acc[mt][nt] = __builtin_amdgcn_mfma_f32_16x16x32_f16(
                    __builtin_bit_cast(f16x8, a0), __builtin_bit_cast(f16x8, bf[nt][0]),
                    acc[mt][nt], 0, 0, 0);
                acc[mt][nt] = __builtin_amdgcn_mfma_f32_16x16x32_f16(
                    __builtin_bit_cast(f16x8, a1), __builtin_bit_cast(f16x8, bf[nt][1]),
                    acc[mt][nt], 0, 0, 0);
            }
        }
    }
    __syncthreads();    // all As/Bs reads done -> Ht/Wt may overwrite
    // ---- phase 2: Ht (f16 transposed, local f) + attention dot partials
#pragma unroll
    for (int mt = 0; mt < 4; ++mt) {
        int mb = wm * 64 + mt * 16;
        float pas[4] = {0.f, 0.f, 0.f, 0.f}, pdd[4] = {0.f, 0.f, 0.f, 0.f};
#pragma unroll
        for (int nt = 0; nt < NT; ++nt) {
#pragma unroll
            for (int r = 0; r < 4; ++r) {
                float hv = acc[mt][nt][r];
                pas[r] += hv * asc[nt];
                pdd[r] += hv * adc[nt];
            }
            int f = (wn * NT + nt) * 16 + col;
            *(uint32_t*)&Ht[f * LDH + mb + kg * 4] = packh2(acc[mt][nt][0], acc[mt][nt][1]);
            *(uint32_t*)&Ht[f * LDH + mb + kg * 4 + 2] = packh2(acc[mt][nt][2], acc[mt][nt][3]);
        }
#pragma unroll
        for (int off = 1; off < 16; off <<= 1)
#pragma unroll
            for (int r = 0; r < 4; ++r) {
                pas[r] += __shfl_xor(pas[r], off, 64);
                pdd[r] += __shfl_xor(pdd[r], off, 64);
            }
        if (col == 0) {
#pragma unroll
            for (int r = 0; r < 4; ++r) {
                int m = mb + kg * 4 + r;
                as_part[wn][m] = pas[r];
                ad_part[wn][m] = pdd[r];
            }
        }
    }
    __syncthreads();
    if (tid < 128) {
#pragma unroll
        for (int hl = 0; hl < HL; ++hl) {
            float sa = 0.f, sd = 0.f;
#pragma unroll
            for (int q = 0; q < WPH; ++q) {
                sa += as_part[hl * WPH + q][tid];
                sd += ad_part[hl * WPH + q][tid];
            }
            as_l[tid * HL + hl] = sa;
            ad_l[tid * HL + hl] = sd;
        }
    }
    __syncthreads();
    // ---- phase 3: aggregation per local head
    for (int h = 0; h < HL; ++h) {
        {
            int v = tid >> 2, ub = (tid & 3) * 32;
            float advv = ad_l[v * HL + h];
            const float* arow = Adj + (size_t)v * 128 + ub;
            float dsum = 0.f;
#pragma unroll
            for (int j = 0; j < 16; ++j) {
                float a0 = arow[2 * j], a1 = arow[2 * j + 1];
                float e0 = as_l[(ub + 2 * j) * HL + h] + advv;
                float e1 = as_l[(ub + 2 * j + 1) * HL + h] + advv;
                e0 = (e0 > 0.f) ? e0 : 0.2f * e0;
                e1 = (e1 > 0.f) ? e1 : 0.2f * e1;
                float w0 = a0 * __expf(e0);
                float w1 = a1 * __expf(e1);
                dsum += w0 + w1;
                *(uint32_t*)&Wt[v * LDH + ub + 2 * j] = packh2(w0, w1);
            }
            dsum += __shfl_xor(dsum, 1, 64);
            dsum += __shfl_xor(dsum, 2, 64);
            if ((tid & 3) == 0) den_l[v] = dsum;
        }
        __syncthreads();
        {
            int vt = w;
            f16x8 af[4];
#pragma unroll
            for (int kt = 0; kt < 4; ++kt) {
                uint4 au = *(const uint4*)&Wt[(vt * 16 + col) * LDH + kt * 32 + kg * 8];
                af[kt] = __builtin_bit_cast(f16x8, au);
            }
            float dn[4];
#pragma unroll
            for (int r = 0; r < 4; ++r) dn[r] = den_l[vt * 16 + kg * 4 + r] + 1e-16f;
#pragma unroll
            for (int ft = 0; ft < 4; ++ft) {
                int f = h * 64 + ft * 16 + col;      // local feature
                f32x4 oacc = {0.f, 0.f, 0.f, 0.f};
#pragma unroll
                for (int kt = 0; kt < 4; ++kt) {
                    uint4 bu = *(const uint4*)&Ht[f * LDH + kt * 32 + kg * 8];
                    oacc = __builtin_amdgcn_mfma_f32_16x16x32_f16(
                        af[kt], __builtin_bit_cast(f16x8, bu), oacc, 0, 0, 0);
                }
                float bv = bias[foff + f];
                if constexpr (!POOLX) {
#pragma unroll
                    for (int r = 0; r < 4; ++r) {
                        int v = vt * 16 + kg * 4 + r;
                        float o = oacc[r] / dn[r] + bv;
                        outG[(size_t)(base + v) * NF + foff + f] = fmaxf(o, 0.f);
                    }
                } else {
                    float ps = 0.f;
#pragma unroll
                    for (int r = 0; r < 4; ++r) ps += fmaxf(oacc[r] / dn[r] + bv, 0.f);
                    ps += __shfl_xor(ps, 16, 64);
                    ps += __shfl_xor(ps, 32, 64);
                    if (kg == 0) psum[w][f] = ps;
                }
            }
        }
        __syncthreads();
    }
    if constexpr (POOLX) {
        if (tid < 64) {
            float s = 0.f;
#pragma unroll
            for (int q = 0; q < 8; ++q) s += psum[q][tid];
            emb[tid] = s;
        }
        __syncthreads();
        int rrow = (g & 31) * 4 + (g >> 5);
        for (int dir = 0; dir < 2; ++dir) {
            const float* W = dir ? Wih_b : Wih_f;
            const float* bi = dir ? bib : bif;
            const float* bh = dir ? bhb : bhf;
            for (int o = tid; o < 1024; o += 512) {
                const float* wr = W + (size_t)o * 64;
                float s = bi[o] + bh[o];
#pragma unroll
                for (int k = 0; k < 64; k += 4) {
                    float4 wv = *(const float4*)(wr + k);
                    s += emb[k] * wv.x + emb[k + 1] * wv.y + emb[k + 2] * wv.z + emb[k + 3] * wv.w;
                }
                outG[dir * 131072 + rrow * 1024 + o] = s;
            }
        }
    }
}

// ---------------- BiLSTM recurrent v7 (LDS h-distribution floor ~75us; control) -----------
__global__ __launch_bounds__(1024, 1) void lstm_kernel(const float* __restrict__ xp,
                                                       const uint32_t* __restrict__ wreg,
                                                       const uint32_t* __restrict__ wtail,
                                                       float* __restrict__ hT) {
    int blk = blockIdx.x;
    int dir = blk >> 2, batch = blk & 3;
    int t = threadIdx.x;                      // gate row 0..1023
    uint32_t wa[96];
    {
        const uint4* ra = (const uint4*)wreg + (size_t)dir * 24 * 1024;
#pragma unroll
        for (int i = 0; i < 24; ++i) {
            uint4 v = ra[i * 1024 + t];
            wa[i * 4 + 0] = v.x; wa[i * 4 + 1] = v.y; wa[i * 4 + 2] = v.z; wa[i * 4 + 3] = v.w;
        }
    }
    __shared__ __align__(16) uint4 wlds[8 * 1024];   // 128 KB tail, [ku][row]
    __shared__ __align__(16) uint32_t h_pk[128];     // h as 128 half2 pairs
    __shared__ float gv[1024];
    {
        const uint4* tsrc = (const uint4*)wtail + (size_t)dir * 8 * 1024;
        for (int i = t; i < 8 * 1024; i += 1024) wlds[i] = tsrc[i];
    }
    if (t < 128) h_pk[t] = 0;
    __syncthreads();
    float creg = 0.f;
    const float* xpb = xp + dir * 131072 + batch * 1024;
#pragma unroll 1
    for (int step = 0; step < 32; ++step) {
        int teff = dir ? (31 - step) : step;
        float xa = xpb[teff * 4096 + t];
        float acc = 0.f;
#pragma unroll
        for (int q = 0; q < 24; ++q) {
            uint4 hq = *(const uint4*)&h_pk[q * 4];   // same-address broadcast b128
            acc = dot2(wa[q * 4 + 0], hq.x, acc);
            acc = dot2(wa[q * 4 + 1], hq.y, acc);
            acc = dot2(wa[q * 4 + 2], hq.z, acc);
            acc = dot2(wa[q * 4 + 3], hq.w, acc);
        }
#pragma unroll
        for (int ku = 0; ku < 8; ++ku) {
            uint4 hq = *(const uint4*)&h_pk[96 + ku * 4];  // broadcast b128
            uint4 qa = wlds[ku * 1024 + t];                // conflict-free b128
            acc = dot2(qa.x, hq.x, acc); acc = dot2(qa.y, hq.y, acc);
            acc = dot2(qa.z, hq.z, acc); acc = dot2(qa.w, hq.w, acc);
        }
        gv[t] = acc + xa;
        __syncthreads();
        if (t < 256) {
            float iv = gv[t], fv = gv[t + 256], gg = gv[t + 512], ov = gv[t + 768];
            creg = sigf(fv) * creg + sigf(iv) * tanhfast(gg);
            float hv = sigf(ov) * tanhfast(creg);
            if (step == 31) hT[(size_t)(dir * 4 + batch) * 256 + t] = hv;
            float hnext = __shfl_down(hv, 1, 64);
            if ((t & 1) == 0) h_pk[t >> 1] = packh2(hv, hnext);
        }
        __syncthreads();
    }
}

// ---------------- heads v2: 129 blocks, 8 threads per output, shfl k-reduce ---------------
__global__ __launch_bounds__(256) void heads_kernel(const float* __restrict__ hT,
                                                    const float* __restrict__ Wmu, const float* __restrict__ bmu,
                                                    const float* __restrict__ Wlv, const float* __restrict__ blv,
                                                    const float* __restrict__ Wpi, const float* __restrict__ bpi,
                                                    float* __restrict__ out) {
    __shared__ __align__(16) float feat[4][512];
    int tid = threadIdx.x;
    for (int i = tid; i < 2048; i += 256) {
        int b = i >> 9, j = i & 511;
        int d = j >> 8, jj = j & 255;
        feat[b][j] = hT[(size_t)(d * 4 + b) * 256 + jj];
    }
    __syncthreads();
    int o = blockIdx.x * 32 + (tid >> 3);     // 32 outputs/block x 8 threads each
    int kp = tid & 7;
    if (o >= 4128) return;
    const float* Wr;
    float bv;
    int kind, m;
    if (o < 2048) { Wr = Wmu + (size_t)o * 512; bv = bmu[o]; kind = 0; m = o; }
    else if (o < 4096) { m = o - 2048; Wr = Wlv + (size_t)m * 512; bv = blv[m]; kind = 1; }
    else { m = o - 4096; Wr = Wpi + (size_t)m * 512; bv = bpi[m]; kind = 2; }
    float s0 = 0.f, s1 = 0.f, s2 = 0.f, s3 = 0.f;
    int k0 = kp * 64;
#pragma unroll
    for (int j = 0; j < 16; ++j) {
        int k = k0 + j * 4;
        float4 wv = *(const float4*)(Wr + k);
        s0 += feat[0][k] * wv.x + feat[0][k + 1] * wv.y + feat[0][k + 2] * wv.z + feat[0][k + 3] * wv.w;
        s1 += feat[1][k] * wv.x + feat[1][k + 1] * wv.y + feat[1][k + 2] * wv.z + feat[1][k + 3] * wv.w;
        s2 += feat[2][k] * wv.x + feat[2][k + 1] * wv.y + feat[2][k + 2] * wv.z + feat[2][k + 3] * wv.w;
        s3 += feat[3][k] * wv.x + feat[3][k + 1] * wv.y + feat[3][k + 2] * wv.z + feat[3][k + 3] * wv.w;
    }
#pragma unroll
    for (int off = 1; off < 8; off <<= 1) {
        s0 += __shfl_xor(s0, off, 64);
        s1 += __shfl_xor(s1, off, 64);
        s2 += __shfl_xor(s2, off, 64);
        s3 += __shfl_xor(s3, off, 64);
    }
    if (kp != 0) return;
    s0 += bv; s1 += bv; s2 += bv; s3 += bv;
    if (kind == 0) {
        out[0 * 2048 + m] = s0; out[1 * 2048 + m] = s1; out[2 * 2048 + m] = s2; out[3 * 2048 + m] = s3;
    } else if (kind == 1) {
        out[8192 + 0 * 2048 + m] = s0; out[8192 + 1 * 2048 + m] = s1;
        out[8192 + 2 * 2048 + m] = s2; out[8192 + 3 * 2048 + m] = s3;
    } else {
        out[16384 + 0 * 32 + m] = s0; out[16384 + 1 * 32 + m] = s1;
        out[16384 + 2 * 32 + m] = s2; out[16384 + 3 * 32 + m] = s3;
    }
}

extern "C" void kernel_launch(void* const* d_in, const int* in_sizes, int n_in,
                              void* d_out, int out_size, void* d_ws, size_t ws_size,
                              hipStream_t stream) {
    const float* x = (const float*)d_in[0];
    const int* ei = (const int*)d_in[1];
    const float* W1 = (const float*)d_in[2];
    const float* as1 = (const float*)d_in[3];
    const float* ad1 = (const float*)d_in[4];
    const float* b1 = (const float*)d_in[5];
    const float* W2 = (const float*)d_in[6];
    const float* as2 = (const float*)d_in[7];
    const float* ad2 = (const float*)d_in[8];
    const float* b2 = (const float*)d_in[9];
    const float* W3 = (const float*)d_in[10];
    const float* as3 = (const float*)d_in[11];
    const float* ad3 = (const float*)d_in[12];
    const float* b3 = (const float*)d_in[13];
    const float* Wih_f = (const float*)d_in[14];
    const float* Whh_f = (const float*)d_in[15];
    const float* bih_f = (const float*)d_in[16];
    const float* bhh_f = (const float*)d_in[17];
    const float* Wih_b = (const float*)d_in[18];
    const float* Whh_b = (const float*)d_in[19];
    const float* bih_b = (const float*)d_in[20];
    const float* bhh_b = (const float*)d_in[21];
    const float* Wmu = (const float*)d_in[22];
    const float* bmu = (const float*)d_in[23];
    const float* Wlv = (const float*)d_in[24];
    const float* blv = (const float*)d_in[25];
    const float* Wpi = (const float*)d_in[26];
    const float* bpi = (const float*)d_in[27];

    float* ws = (float*)d_ws;
    float* buf1 = ws;                        // [0, 4194304)
    float* buf2 = ws + 4194304;              // [4194304, 8388608)
    float* Adj = ws + 8388608;               // 16384
    float* xp = ws + 8404992;                // 262144
    float* hT = ws + 8667136;                // 2048
    _Float16* W1t = (_Float16*)(ws + 8669184);   // 16384 f16
    _Float16* W2t = (_Float16*)(ws + 8677376);   // 65536 f16
    _Float16* W3t = (_Float16*)(ws + 8710144);   // 16384 f16 -> ends 8718336
    uint32_t* wreg = (uint32_t*)(ws + 8718336);  // 196608 u32 (dedicated, no overlap)
    uint32_t* wtail = wreg + 196608;             // 65536 u32
    float* out = (float*)d_out;

    // prep: adjacency + f16 GAT weights + LSTM weight pack (one dispatch)
    prep_kernel<<<232, 256, 0, stream>>>(ei, Adj, W1, W2, W3, W1t, W2t, W3t,
                                         Whh_f, Whh_b, wreg, wtail);
    // GAT layers (fused; layers 1-2 head-split over 256 blocks)
    fl_kernel<64, 128, 256, false><<<dim3(128, 2), 512, 0, stream>>>(x, W1t, as1, ad1, Adj, b1,
        Wih_f, bih_f, bhh_f, Wih_b, bih_b, bhh_b, buf1);
    fl_kernel<256, 128, 256, false><<<dim3(128, 2), 512, 0, stream>>>(buf1, W2t, as2, ad2, Adj, b2,
        Wih_f, bih_f, bhh_f, Wih_b, bih_b, bhh_b, buf2);
    fl_kernel<256, 64, 64, true><<<dim3(128, 1), 512, 0, stream>>>(buf2, W3t, as3, ad3, Adj, b3,
        Wih_f, bih_f, bhh_f, Wih_b, bih_b, bhh_b, xp);
    // recurrent + heads
    lstm_kernel<<<8, 1024, 0, stream>>>(xp, wreg, wtail, hT);
    heads_kernel<<<129, 256, 0, stream>>>(hT, Wmu, bmu, Wlv, blv, Wpi, bpi, out);
}